// Round 1
// baseline (10843.826 us; speedup 1.0000x reference)
//
#include <hip/hip_runtime.h>
#include <hip/hip_bf16.h>
#include <math.h>

// Problem constants
constexpr int HH = 40, WW = 100, HW = 4000, NB = 16;
constexpr int DIM = 134;     // inst branch channels
constexpr int MDIM = 256;    // mask branch channels
constexpr int NINST = 4;     // instances per image
constexpr int KD = 128;      // kernel dim
constexpr int NCLS = 2;

// ---------------------------------------------------------------------------
// Implicit-GEMM conv kernel.
// View conv as C[m][n] = sum_k A[m][k] * B[k][n]
//   m = b*4000 + h*100 + w   (M = 64000)
//   n = cout
//   k = cin*9 + r*3 + s      (3x3) or k = cin (1x1)
// B[k][n] = Wt[n*K + k] (OIHW weight is exactly n-major, k-minor)
// MODE 0: plain 3x3 SAME conv
// MODE 1: coord-augmented 3x3 (cin==0 -> x coord, cin==1 -> y coord, rest X)
// MODE 2: 1x1 conv
// BM=BN=BK=64, 256 threads, 4x4 register tile per thread.
// ---------------------------------------------------------------------------
template <int MODE>
__global__ __launch_bounds__(256) void conv_gemm(
    const float* __restrict__ X, const float* __restrict__ Wt,
    const float* __restrict__ bias, float* __restrict__ Y,
    int Cin, int Cout, int K, int do_relu)
{
    __shared__ float As[64][64];   // [k][m], conflict-free
    __shared__ float Bs[64][68];   // [k][n], padded row: 68*4=272B, 16B-aligned rows

    const int tid = threadIdx.x;
    const int m0 = blockIdx.x * 64;
    const int n0 = blockIdx.y * 64;
    const int tx = tid & 15;        // n-tile index
    const int ty = tid >> 4;        // m-tile index

    // A staging: fixed m per thread, 16 k's
    const int mmA = tid & 63;
    const int kgrp = tid >> 6;      // 0..3
    const int mA = m0 + mmA;
    const int bA = mA / HW;
    const int hwA = mA - bA * HW;
    const int hA = hwA / WW;
    const int wA = hwA - hA * WW;
    // B staging: fixed k per thread, 16 n's
    const int kkB = tid & 63;

    float acc[4][4] = {};

    for (int k0 = 0; k0 < K; k0 += 64) {
        // ---- stage A tile (im2col gather) ----
        #pragma unroll
        for (int i = 0; i < 16; ++i) {
            const int kk = i * 4 + kgrp;
            const int k = k0 + kk;
            float v = 0.f;
            if (k < K) {
                if (MODE == 2) {
                    v = X[(bA * Cin + k) * HW + hwA];
                } else {
                    const int cin = k / 9;
                    const int rs = k - cin * 9;
                    const int r = rs / 3;
                    const int s = rs - r * 3;
                    const int hj = hA + r - 1;
                    const int wj = wA + s - 1;
                    if (hj >= 0 && hj < HH && wj >= 0 && wj < WW) {
                        if (MODE == 1) {
                            if (cin == 0)      v = -1.f + 2.f * (float)wj / 99.f;
                            else if (cin == 1) v = -1.f + 2.f * (float)hj / 39.f;
                            else v = X[((bA * (Cin - 2) + (cin - 2)) * HH + hj) * WW + wj];
                        } else {
                            v = X[((bA * Cin + cin) * HH + hj) * WW + wj];
                        }
                    }
                }
            }
            As[kk][mmA] = v;
        }
        // ---- stage B tile (weights, coalesced along k) ----
        #pragma unroll
        for (int i = 0; i < 16; ++i) {
            const int n = i * 4 + kgrp;
            const int gn = n0 + n;
            const int k = k0 + kkB;
            float v = 0.f;
            if (gn < Cout && k < K) v = Wt[gn * K + k];
            Bs[kkB][n] = v;
        }
        __syncthreads();

        // ---- inner product ----
        #pragma unroll 8
        for (int kk = 0; kk < 64; ++kk) {
            const float4 av = *(const float4*)(&As[kk][ty << 2]);
            const float4 bv = *(const float4*)(&Bs[kk][tx << 2]);
            const float a4[4] = {av.x, av.y, av.z, av.w};
            const float b4[4] = {bv.x, bv.y, bv.z, bv.w};
            #pragma unroll
            for (int i2 = 0; i2 < 4; ++i2)
                #pragma unroll
                for (int j2 = 0; j2 < 4; ++j2)
                    acc[i2][j2] = fmaf(a4[i2], b4[j2], acc[i2][j2]);
        }
        __syncthreads();
    }

    // ---- epilogue: bias (+ReLU), NCHW scatter ----
    #pragma unroll
    for (int j2 = 0; j2 < 4; ++j2) {
        const int n = n0 + (tx << 2) + j2;
        if (n >= Cout) continue;
        const float bv = bias[n];
        #pragma unroll
        for (int i2 = 0; i2 < 4; ++i2) {
            const int m = m0 + (ty << 2) + i2;
            const int b = m / HW;
            const int hw = m - b * HW;
            float v = acc[i2][j2] + bv;
            if (do_relu) v = fmaxf(v, 0.f);
            Y[(b * Cout + n) * HW + hw] = v;
        }
    }
}

// ---------------------------------------------------------------------------
// iam conv: N=4 outputs, Cin=134, 3x3 SAME. One thread per spatial position.
// ---------------------------------------------------------------------------
__global__ __launch_bounds__(256) void iam_conv(
    const float* __restrict__ F, const float* __restrict__ Wt,
    const float* __restrict__ bias, float* __restrict__ iam)
{
    __shared__ float ws[NINST * DIM * 9];   // 4824 floats
    const int tid = threadIdx.x;
    for (int i = tid; i < NINST * DIM * 9; i += 256) ws[i] = Wt[i];
    __syncthreads();

    const int m = blockIdx.x * 256 + tid;   // < 64000
    const int b = m / HW;
    const int hw = m - b * HW;
    const int h = hw / WW;
    const int w = hw - h * WW;

    float acc[NINST] = {bias[0], bias[1], bias[2], bias[3]};
    for (int cin = 0; cin < DIM; ++cin) {
        const float* fb = &F[(b * DIM + cin) * HW];
        #pragma unroll
        for (int r = 0; r < 3; ++r) {
            const int hj = h + r - 1;
            if (hj < 0 || hj >= HH) continue;
            #pragma unroll
            for (int s = 0; s < 3; ++s) {
                const int wj = w + s - 1;
                if (wj < 0 || wj >= WW) continue;
                const float fv = fb[hj * WW + wj];
                const int widx = cin * 9 + r * 3 + s;
                #pragma unroll
                for (int n = 0; n < NINST; ++n)
                    acc[n] = fmaf(fv, ws[n * (DIM * 9) + widx], acc[n]);
            }
        }
    }
    #pragma unroll
    for (int n = 0; n < NINST; ++n)
        iam[(b * NINST + n) * HW + hw] = acc[n];
}

__device__ __forceinline__ float sigmoidf_dev(float x) {
    return 1.f / (1.f + expf(-x));
}

// ---------------------------------------------------------------------------
// Per (b,n): argmax of sigmoid(iam) (first-index tie-break) and sum of sigmoid.
// ---------------------------------------------------------------------------
__global__ __launch_bounds__(256) void stats_kernel(
    const float* __restrict__ iam, int* __restrict__ pos, float* __restrict__ denom)
{
    const int i = blockIdx.x;   // 0..63 = b*4+n
    const int tid = threadIdx.x;
    const float* p = &iam[i * HW];

    float bm = -1e30f; int bi = 0; float sum = 0.f;
    for (int l = tid; l < HW; l += 256) {
        const float s = sigmoidf_dev(p[l]);
        sum += s;
        if (s > bm) { bm = s; bi = l; }   // strict > keeps first occurrence
    }
    __shared__ float sm[256]; __shared__ int si[256]; __shared__ float ss[256];
    sm[tid] = bm; si[tid] = bi; ss[tid] = sum;
    __syncthreads();
    for (int off = 128; off > 0; off >>= 1) {
        if (tid < off) {
            ss[tid] += ss[tid + off];
            const float m2 = sm[tid + off]; const int i2 = si[tid + off];
            if (m2 > sm[tid] || (m2 == sm[tid] && i2 < si[tid])) { sm[tid] = m2; si[tid] = i2; }
        }
        __syncthreads();
    }
    if (tid == 0) { pos[i] = si[0]; denom[i] = fmaxf(ss[0], 1e-6f); }
}

// ---------------------------------------------------------------------------
// inst[b][n][c] = (sum_l sigmoid(iam[b][n][l]) * f[b][c][l]) / denom[b*4+n]
// One block per (b, c).
// ---------------------------------------------------------------------------
__global__ __launch_bounds__(256) void inst_kernel(
    const float* __restrict__ iam, const float* __restrict__ F,
    const float* __restrict__ denom, float* __restrict__ inst)
{
    const int b = blockIdx.x;
    const int c = blockIdx.y;
    const int tid = threadIdx.x;
    const float* fp = &F[(b * DIM + c) * HW];

    float acc[NINST] = {};
    for (int l = tid; l < HW; l += 256) {
        const float fv = fp[l];
        #pragma unroll
        for (int n = 0; n < NINST; ++n) {
            const float s = sigmoidf_dev(iam[(b * NINST + n) * HW + l]);
            acc[n] = fmaf(s, fv, acc[n]);
        }
    }
    __shared__ float red[NINST][256];
    #pragma unroll
    for (int n = 0; n < NINST; ++n) red[n][tid] = acc[n];
    __syncthreads();
    for (int off = 128; off > 0; off >>= 1) {
        if (tid < off) {
            #pragma unroll
            for (int n = 0; n < NINST; ++n) red[n][tid] += red[n][tid + off];
        }
        __syncthreads();
    }
    if (tid < NINST)
        inst[(b * NINST + tid) * DIM + c] = red[tid][0] / denom[b * NINST + tid];
}

// ---------------------------------------------------------------------------
// pred_logits (out) and pred_kernel (ws) from inst.  One block per instance.
// ---------------------------------------------------------------------------
__global__ __launch_bounds__(128) void head_kernel(
    const float* __restrict__ inst,
    const float* __restrict__ cls_w, const float* __restrict__ cls_b,
    const float* __restrict__ mk_w, const float* __restrict__ mk_b,
    float* __restrict__ out_logits, float* __restrict__ pk)
{
    const int i = blockIdx.x;   // instance
    const int tid = threadIdx.x;
    __shared__ float iv[DIM];
    for (int c = tid; c < DIM; c += 128) iv[c] = inst[i * DIM + c];
    __syncthreads();

    float a = mk_b[tid];
    for (int c = 0; c < DIM; ++c) a = fmaf(iv[c], mk_w[tid * DIM + c], a);
    pk[i * KD + tid] = a;

    if (tid < NCLS) {
        float g = cls_b[tid];
        for (int c = 0; c < DIM; ++c) g = fmaf(iv[c], cls_w[tid * DIM + c], g);
        out_logits[i * NCLS + tid] = g;
    }
}

// ---------------------------------------------------------------------------
// mask_params / reg_params: gather rows of batch-0 features at pos[i].
// (Reference quirk preserved: params[pos] always indexes batch 0.)
// ---------------------------------------------------------------------------
__global__ void gather_kernel(
    const float* __restrict__ F, const int* __restrict__ pos,
    float* __restrict__ outm, float* __restrict__ outr)
{
    const int i = blockIdx.x;
    const int c = threadIdx.x;
    if (c >= DIM) return;
    const int p = pos[i];
    const float v = F[c * HW + p];   // batch 0 row
    if (c < 67) outm[i * 67 + c] = v;
    else        outr[i * 67 + (c - 67)] = v;
}

// ---------------------------------------------------------------------------
// pred_masks[b][n][l] = sum_k pk[b][n][k] * mf[b][k][l]
// ---------------------------------------------------------------------------
__global__ __launch_bounds__(256) void maskout_kernel(
    const float* __restrict__ pk, const float* __restrict__ mf,
    float* __restrict__ outm)
{
    const int b = blockIdx.x;
    const int lc = blockIdx.y;
    const int tid = threadIdx.x;
    __shared__ float pks[NINST][KD];
    for (int i = tid; i < NINST * KD; i += 256) pks[i >> 7][i & 127] = pk[b * NINST * KD + i];
    __syncthreads();
    const int l = lc * 256 + tid;
    if (l >= HW) return;
    float acc[NINST] = {};
    for (int k = 0; k < KD; ++k) {
        const float mv = mf[(b * KD + k) * HW + l];
        #pragma unroll
        for (int n = 0; n < NINST; ++n) acc[n] = fmaf(pks[n][k], mv, acc[n]);
    }
    #pragma unroll
    for (int n = 0; n < NINST; ++n)
        outm[(b * NINST + n) * HW + l] = acc[n];
}

// ---------------------------------------------------------------------------
extern "C" void kernel_launch(void* const* d_in, const int* in_sizes, int n_in,
                              void* d_out, int out_size, void* d_ws, size_t ws_size,
                              hipStream_t stream)
{
    const float* features = (const float*)d_in[0];
    const float* iw0 = (const float*)d_in[1];
    const float* ib0 = (const float*)d_in[2];
    const float* iw1 = (const float*)d_in[3];
    const float* ib1 = (const float*)d_in[4];
    const float* iw2 = (const float*)d_in[5];
    const float* ib2 = (const float*)d_in[6];
    const float* iw3 = (const float*)d_in[7];
    const float* ib3 = (const float*)d_in[8];
    const float* iam_w = (const float*)d_in[9];
    const float* iam_b = (const float*)d_in[10];
    const float* cls_w = (const float*)d_in[11];
    const float* cls_b = (const float*)d_in[12];
    const float* mk_w = (const float*)d_in[13];
    const float* mk_b = (const float*)d_in[14];
    const float* mw0 = (const float*)d_in[15];
    const float* mb0 = (const float*)d_in[16];
    const float* mw1 = (const float*)d_in[17];
    const float* mb1 = (const float*)d_in[18];
    const float* mw2 = (const float*)d_in[19];
    const float* mb2 = (const float*)d_in[20];
    const float* mw3 = (const float*)d_in[21];
    const float* mb3 = (const float*)d_in[22];
    const float* pw = (const float*)d_in[23];
    const float* pb = (const float*)d_in[24];

    // workspace layout (bytes)
    char* ws = (char*)d_ws;
    float* R1    = (float*)(ws);                     // 16*256*4000 f = 65,536,000 B
    float* R2    = (float*)(ws + 65536000);          // 65,536,000 B
    float* iamb  = (float*)(ws + 131072000);         // 16*4*4000 f = 1,024,000 B
    int*   pos   = (int*)  (ws + 132096000);         // 256 B
    float* denom = (float*)(ws + 132096256);         // 256 B
    float* instb = (float*)(ws + 132096512);         // 64*134 f = 34,304 B
    float* pk    = (float*)(ws + 132130816);         // 64*128 f = 32,768 B
    // total: 132,163,584 B

    float* out_logits = (float*)d_out;              // 64*2
    float* out_mask   = out_logits + 64 * NCLS;     // 64*67
    float* out_reg    = out_mask + 64 * 67;         // 64*67
    float* out_masks  = out_reg + 64 * 67;          // 64*4000

    const dim3 blk(256);

    // ---- inst branch ----
    conv_gemm<1><<<dim3(1000, 3), blk, 0, stream>>>(features, iw0, ib0, R1, 258, DIM, 2322, 1);
    conv_gemm<0><<<dim3(1000, 3), blk, 0, stream>>>(R1, iw1, ib1, R2, DIM, DIM, 1206, 1);
    conv_gemm<0><<<dim3(1000, 3), blk, 0, stream>>>(R2, iw2, ib2, R1, DIM, DIM, 1206, 1);
    conv_gemm<0><<<dim3(1000, 3), blk, 0, stream>>>(R1, iw3, ib3, R2, DIM, DIM, 1206, 1);

    iam_conv<<<dim3(250), blk, 0, stream>>>(R2, iam_w, iam_b, iamb);
    stats_kernel<<<dim3(64), blk, 0, stream>>>(iamb, pos, denom);
    inst_kernel<<<dim3(16, DIM), blk, 0, stream>>>(iamb, R2, denom, instb);
    head_kernel<<<dim3(64), dim3(128), 0, stream>>>(instb, cls_w, cls_b, mk_w, mk_b, out_logits, pk);
    gather_kernel<<<dim3(64), dim3(192), 0, stream>>>(R2, pos, out_mask, out_reg);

    // ---- mask branch (R1/R2 free for reuse after the gathers above) ----
    conv_gemm<1><<<dim3(1000, 4), blk, 0, stream>>>(features, mw0, mb0, R1, 258, MDIM, 2322, 1);
    conv_gemm<0><<<dim3(1000, 4), blk, 0, stream>>>(R1, mw1, mb1, R2, MDIM, MDIM, 2304, 1);
    conv_gemm<0><<<dim3(1000, 4), blk, 0, stream>>>(R2, mw2, mb2, R1, MDIM, MDIM, 2304, 1);
    conv_gemm<0><<<dim3(1000, 4), blk, 0, stream>>>(R1, mw3, mb3, R2, MDIM, MDIM, 2304, 1);
    conv_gemm<2><<<dim3(1000, 2), blk, 0, stream>>>(R2, pw, pb, R1, MDIM, KD, MDIM, 0);

    maskout_kernel<<<dim3(16, 16), blk, 0, stream>>>(pk, R1, out_masks);
}

// Round 2
// 4764.499 us; speedup vs baseline: 2.2760x; 2.2760x over previous
//
#include <hip/hip_runtime.h>
#include <hip/hip_bf16.h>
#include <math.h>

constexpr int HH = 40, WW = 100, HW = 4000;
constexpr int DIM = 134;     // inst branch channels
constexpr int MDIM = 256;    // mask branch channels
constexpr int NINST = 4;
constexpr int KD = 128;
constexpr int NCLS = 2;

typedef short s16x8 __attribute__((ext_vector_type(8)));
typedef float f32x4 __attribute__((ext_vector_type(4)));
typedef unsigned int u32;
typedef unsigned int u32x4 __attribute__((ext_vector_type(4)));
typedef unsigned short u16x4 __attribute__((ext_vector_type(4)));

__device__ __forceinline__ unsigned short f2bf(float f) {
    __hip_bfloat16 h = __float2bfloat16(f);
    unsigned short b; __builtin_memcpy(&b, &h, 2); return b;
}
__device__ __forceinline__ float bf2f(unsigned short b) {
    __hip_bfloat16 h; __builtin_memcpy(&h, &b, 2); return __bfloat162float(h);
}

// ---------------------------------------------------------------------------
// Weight repack: OIHW fp32 -> Wp[(rs*Cout + n)*Cpad + c] bf16 hi (+ lo).
// Zero-pads c in [Cin, Cpad).
// ---------------------------------------------------------------------------
__global__ __launch_bounds__(256) void repack_w(
    const float* __restrict__ W, unsigned short* __restrict__ Wh,
    unsigned short* __restrict__ Wl, int Cout, int Cin, int RS, int Cpad,
    int do_lo)
{
    const int idx = blockIdx.x * 256 + threadIdx.x;
    const int total = RS * Cout * Cpad;
    if (idx >= total) return;
    const int c = idx % Cpad;
    const int t = idx / Cpad;
    const int n = t % Cout;
    const int rs = t / Cout;
    float v = (c < Cin) ? W[(n * Cin + c) * RS + rs] : 0.f;
    const unsigned short hb = f2bf(v);
    Wh[idx] = hb;
    if (do_lo) Wl[idx] = f2bf(v - bf2f(hb));
}

// ---------------------------------------------------------------------------
// bf16-MFMA implicit-GEMM conv, rs-decomposed.
//   Y[m][n] = sum_{rs} sum_{cin} A_rs[m][cin] * W[n][cin][rs]
// BM=128, BK=32, BN template (64 or 128). 256 threads = 4 waves (2m x 2n).
// MODE 0: plain 3x3 SAME; MODE 1: coord-augmented 3x3 (c=0 x-coord, c=1
// y-coord, rest X[c-2]); MODE 2: 1x1.
// SPLIT 1: single bf16 pass. SPLIT 3: a=ah+al, b=bh+bl; ah*bh+ah*bl+al*bh
// (drops al*bl ~2^-18) for ~1e-5 relative accuracy (argmax-safe).
// LDS is fragment-ordered: u32 off(m,k) = ((f*4+g)*16 + r)*4 + k2 with
// f=m>>4, r=m&15, g=k>>3, k2=(k&7)>>1 -> ds_read_b128 conflict-free.
// ---------------------------------------------------------------------------
template <int MODE, int SPLIT, int BN, int IN_BF16, int OUT_BF16>
__global__ __launch_bounds__(256) void conv_mfma(
    const void* __restrict__ Xv, const unsigned short* __restrict__ Wh,
    const unsigned short* __restrict__ Wl, const float* __restrict__ bias,
    void* __restrict__ Yv, int Cin, int Cout, int do_relu)
{
    constexpr int NRS = (MODE == 2) ? 1 : 9;
    constexpr int FN = BN / 32;            // B fragments per wave
    const int CinX = (MODE == 1) ? (Cin - 2) : Cin;   // actual X channels
    const int Cpad = (Cin + 31) & ~31;
    const int nChunk = Cpad >> 5;

    __shared__ u32 lsA[2048];
    __shared__ u32 lsAlo[(SPLIT == 3) ? 2048 : 4];
    __shared__ u32 lsB[BN * 16];
    __shared__ u32 lsBlo[(SPLIT == 3) ? BN * 16 : 4];

    const int tid = threadIdx.x;
    const int m0 = blockIdx.y * 128;
    const int n0 = blockIdx.x * BN;

    // ---- per-thread A staging precompute (2 (m,g) pairs) ----
    int mloc_[2], g_[2], base_[2], h_[2], w_[2];
    #pragma unroll
    for (int q = 0; q < 2; ++q) {
        const int p = tid + q * 256;
        const int mloc = p & 127;
        const int g = p >> 7;
        const int m = m0 + mloc;
        const int b = m / HW;
        const int hw = m - b * HW;
        const int h = hw / WW;
        const int w = hw - h * WW;
        mloc_[q] = mloc; g_[q] = g; h_[q] = h; w_[q] = w;
        base_[q] = b * CinX * HW + hw;
    }

    // ---- wave/lane constants for MFMA ----
    const int lane = tid & 63;
    const int wid = tid >> 6;
    const int wm = (wid & 1) * 64;
    const int wn = (wid >> 1) * (BN / 2);
    const int gL = lane >> 4;
    const int rL = lane & 15;

    f32x4 acc[4][FN];
    #pragma unroll
    for (int i = 0; i < 4; ++i)
        #pragma unroll
        for (int j = 0; j < FN; ++j)
            acc[i][j] = (f32x4){0.f, 0.f, 0.f, 0.f};

    for (int c0i = 0; c0i < nChunk; ++c0i) {
        const int c0 = c0i * 32;
        #pragma unroll 1
        for (int rs = 0; rs < NRS; ++rs) {
            const int r = (MODE == 2) ? 1 : (rs / 3);
            const int s = (MODE == 2) ? 1 : (rs - 3 * (rs / 3));
            const int off = (r - 1) * WW + (s - 1);

            // ---- stage A ----
            #pragma unroll
            for (int q = 0; q < 2; ++q) {
                const int hj = h_[q] + r - 1;
                const int wj = w_[q] + s - 1;
                const bool valid = (MODE == 2) ? true
                    : ((unsigned)hj < (unsigned)HH && (unsigned)wj < (unsigned)WW);
                const int cg = c0 + g_[q] * 8;
                const int idx0 = base_[q] + (cg - ((MODE == 1) ? 2 : 0)) * HW + off;
                u32 hp[4] = {0, 0, 0, 0}, lp[4] = {0, 0, 0, 0};
                if (valid) {
                    #pragma unroll
                    for (int j = 0; j < 8; ++j) {
                        const int c = cg + j;
                        if (c < Cin) {
                            unsigned short hb, lb = 0;
                            if (MODE == 1 && c < 2) {
                                const float v = (c == 0) ? (-1.f + 2.f * (float)wj / 99.f)
                                                         : (-1.f + 2.f * (float)hj / 39.f);
                                hb = f2bf(v);
                                if (SPLIT == 3) lb = f2bf(v - bf2f(hb));
                            } else if (IN_BF16) {
                                hb = ((const unsigned short*)Xv)[idx0 + j * HW];
                            } else {
                                const float v = ((const float*)Xv)[idx0 + j * HW];
                                hb = f2bf(v);
                                if (SPLIT == 3) lb = f2bf(v - bf2f(hb));
                            }
                            hp[j >> 1] |= (u32)hb << ((j & 1) * 16);
                            if (SPLIT == 3) lp[j >> 1] |= (u32)lb << ((j & 1) * 16);
                        }
                    }
                }
                const int ao = (((mloc_[q] >> 4) * 4 + g_[q]) * 16 + (mloc_[q] & 15)) * 4;
                *reinterpret_cast<u32x4*>(&lsA[ao]) = *reinterpret_cast<const u32x4*>(hp);
                if (SPLIT == 3)
                    *reinterpret_cast<u32x4*>(&lsAlo[ao]) = *reinterpret_cast<const u32x4*>(lp);
            }

            // ---- stage B (pre-repacked bf16 weights, 16B-aligned) ----
            constexpr int NP = (BN == 64) ? 1 : 2;
            #pragma unroll
            for (int q = 0; q < NP; ++q) {
                const int p = tid + q * 256;
                const int n = p & (BN - 1);
                const int g = p >> ((BN == 64) ? 6 : 7);
                const int gn = n0 + n;
                u32 hp[4] = {0, 0, 0, 0}, lp[4] = {0, 0, 0, 0};
                if (gn < Cout) {
                    const size_t wi = ((size_t)rs * Cout + gn) * Cpad + c0 + g * 8;
                    *reinterpret_cast<u32x4*>(hp) =
                        *reinterpret_cast<const u32x4*>(Wh + wi);
                    if (SPLIT == 3)
                        *reinterpret_cast<u32x4*>(lp) =
                            *reinterpret_cast<const u32x4*>(Wl + wi);
                }
                const int bo = (((n >> 4) * 4 + g) * 16 + (n & 15)) * 4;
                *reinterpret_cast<u32x4*>(&lsB[bo]) = *reinterpret_cast<const u32x4*>(hp);
                if (SPLIT == 3)
                    *reinterpret_cast<u32x4*>(&lsBlo[bo]) = *reinterpret_cast<const u32x4*>(lp);
            }
            __syncthreads();

            // ---- fragments + MFMA ----
            s16x8 ah[4], bh[FN];
            s16x8 al[4] = {}, bl[FN] = {};
            #pragma unroll
            for (int fm = 0; fm < 4; ++fm) {
                const int ao = ((((wm >> 4) + fm) * 4 + gL) * 16 + rL) * 4;
                ah[fm] = *reinterpret_cast<const s16x8*>(&lsA[ao]);
                if (SPLIT == 3) al[fm] = *reinterpret_cast<const s16x8*>(&lsAlo[ao]);
            }
            #pragma unroll
            for (int fn = 0; fn < FN; ++fn) {
                const int bo = ((((wn >> 4) + fn) * 4 + gL) * 16 + rL) * 4;
                bh[fn] = *reinterpret_cast<const s16x8*>(&lsB[bo]);
                if (SPLIT == 3) bl[fn] = *reinterpret_cast<const s16x8*>(&lsBlo[bo]);
            }
            #pragma unroll
            for (int fm = 0; fm < 4; ++fm)
                #pragma unroll
                for (int fn = 0; fn < FN; ++fn) {
                    acc[fm][fn] = __builtin_amdgcn_mfma_f32_16x16x32_bf16(
                        ah[fm], bh[fn], acc[fm][fn], 0, 0, 0);
                    if (SPLIT == 3) {
                        acc[fm][fn] = __builtin_amdgcn_mfma_f32_16x16x32_bf16(
                            ah[fm], bl[fn], acc[fm][fn], 0, 0, 0);
                        acc[fm][fn] = __builtin_amdgcn_mfma_f32_16x16x32_bf16(
                            al[fm], bh[fn], acc[fm][fn], 0, 0, 0);
                    }
                }
            __syncthreads();
        }
    }

    // ---- epilogue: bias (+ReLU), NCHW store ----
    #pragma unroll
    for (int fn = 0; fn < FN; ++fn) {
        const int n = n0 + wn + fn * 16 + rL;
        if (n >= Cout) continue;
        const float bv = bias[n];
        #pragma unroll
        for (int fm = 0; fm < 4; ++fm) {
            const int mBase = m0 + wm + fm * 16 + gL * 4;
            const int b = mBase / HW;
            const int hwB = mBase - b * HW;          // mBase%4==0, HW%4==0 -> same b for +0..3
            f32x4 v = acc[fm][fn];
            #pragma unroll
            for (int i = 0; i < 4; ++i) {
                float x = v[i] + bv;
                if (do_relu) x = fmaxf(x, 0.f);
                v[i] = x;
            }
            if (OUT_BF16) {
                u16x4 pk;
                #pragma unroll
                for (int i = 0; i < 4; ++i) pk[i] = f2bf(v[i]);
                *reinterpret_cast<u16x4*>(
                    &((unsigned short*)Yv)[(size_t)(b * Cout + n) * HW + hwB]) = pk;
            } else {
                *reinterpret_cast<f32x4*>(
                    &((float*)Yv)[(size_t)(b * Cout + n) * HW + hwB]) = v;
            }
        }
    }
}

// ---------------------------------------------------------------------------
// iam conv: N=4 outputs, Cin=134, 3x3 SAME (fp32, reads fp32 f).
// ---------------------------------------------------------------------------
__global__ __launch_bounds__(256) void iam_conv(
    const float* __restrict__ F, const float* __restrict__ Wt,
    const float* __restrict__ bias, float* __restrict__ iam)
{
    __shared__ float ws[NINST * DIM * 9];
    const int tid = threadIdx.x;
    for (int i = tid; i < NINST * DIM * 9; i += 256) ws[i] = Wt[i];
    __syncthreads();

    const int m = blockIdx.x * 256 + tid;
    const int b = m / HW;
    const int hw = m - b * HW;
    const int h = hw / WW;
    const int w = hw - h * WW;

    float acc[NINST] = {bias[0], bias[1], bias[2], bias[3]};
    for (int cin = 0; cin < DIM; ++cin) {
        const float* fb = &F[(b * DIM + cin) * HW];
        #pragma unroll
        for (int r = 0; r < 3; ++r) {
            const int hj = h + r - 1;
            if (hj < 0 || hj >= HH) continue;
            #pragma unroll
            for (int s = 0; s < 3; ++s) {
                const int wj = w + s - 1;
                if (wj < 0 || wj >= WW) continue;
                const float fv = fb[hj * WW + wj];
                const int widx = cin * 9 + r * 3 + s;
                #pragma unroll
                for (int n = 0; n < NINST; ++n)
                    acc[n] = fmaf(fv, ws[n * (DIM * 9) + widx], acc[n]);
            }
        }
    }
    #pragma unroll
    for (int n = 0; n < NINST; ++n)
        iam[(b * NINST + n) * HW + hw] = acc[n];
}

__device__ __forceinline__ float sigmoidf_dev(float x) {
    return 1.f / (1.f + expf(-x));
}

__global__ __launch_bounds__(256) void stats_kernel(
    const float* __restrict__ iam, int* __restrict__ pos, float* __restrict__ denom)
{
    const int i = blockIdx.x;
    const int tid = threadIdx.x;
    const float* p = &iam[i * HW];

    float bm = -1e30f; int bi = 0; float sum = 0.f;
    for (int l = tid; l < HW; l += 256) {
        const float s = sigmoidf_dev(p[l]);
        sum += s;
        if (s > bm) { bm = s; bi = l; }
    }
    __shared__ float sm[256]; __shared__ int si[256]; __shared__ float ss[256];
    sm[tid] = bm; si[tid] = bi; ss[tid] = sum;
    __syncthreads();
    for (int off = 128; off > 0; off >>= 1) {
        if (tid < off) {
            ss[tid] += ss[tid + off];
            const float m2 = sm[tid + off]; const int i2 = si[tid + off];
            if (m2 > sm[tid] || (m2 == sm[tid] && i2 < si[tid])) { sm[tid] = m2; si[tid] = i2; }
        }
        __syncthreads();
    }
    if (tid == 0) { pos[i] = si[0]; denom[i] = fmaxf(ss[0], 1e-6f); }
}

__global__ __launch_bounds__(256) void inst_kernel(
    const float* __restrict__ iam, const float* __restrict__ F,
    const float* __restrict__ denom, float* __restrict__ inst)
{
    const int b = blockIdx.x;
    const int c = blockIdx.y;
    const int tid = threadIdx.x;
    const float* fp = &F[(b * DIM + c) * HW];

    float acc[NINST] = {};
    for (int l = tid; l < HW; l += 256) {
        const float fv = fp[l];
        #pragma unroll
        for (int n = 0; n < NINST; ++n) {
            const float s = sigmoidf_dev(iam[(b * NINST + n) * HW + l]);
            acc[n] = fmaf(s, fv, acc[n]);
        }
    }
    __shared__ float red[NINST][256];
    #pragma unroll
    for (int n = 0; n < NINST; ++n) red[n][tid] = acc[n];
    __syncthreads();
    for (int off = 128; off > 0; off >>= 1) {
        if (tid < off) {
            #pragma unroll
            for (int n = 0; n < NINST; ++n) red[n][tid] += red[n][tid + off];
        }
        __syncthreads();
    }
    if (tid < NINST)
        inst[(b * NINST + tid) * DIM + c] = red[tid][0] / denom[b * NINST + tid];
}

__global__ __launch_bounds__(128) void head_kernel(
    const float* __restrict__ inst,
    const float* __restrict__ cls_w, const float* __restrict__ cls_b,
    const float* __restrict__ mk_w, const float* __restrict__ mk_b,
    float* __restrict__ out_logits, float* __restrict__ pk)
{
    const int i = blockIdx.x;
    const int tid = threadIdx.x;
    __shared__ float iv[DIM];
    for (int c = tid; c < DIM; c += 128) iv[c] = inst[i * DIM + c];
    __syncthreads();

    float a = mk_b[tid];
    for (int c = 0; c < DIM; ++c) a = fmaf(iv[c], mk_w[tid * DIM + c], a);
    pk[i * KD + tid] = a;

    if (tid < NCLS) {
        float g = cls_b[tid];
        for (int c = 0; c < DIM; ++c) g = fmaf(iv[c], cls_w[tid * DIM + c], g);
        out_logits[i * NCLS + tid] = g;
    }
}

__global__ void gather_kernel(
    const float* __restrict__ F, const int* __restrict__ pos,
    float* __restrict__ outm, float* __restrict__ outr)
{
    const int i = blockIdx.x;
    const int c = threadIdx.x;
    if (c >= DIM) return;
    const int p = pos[i];
    const float v = F[c * HW + p];   // batch-0 quirk preserved
    if (c < 67) outm[i * 67 + c] = v;
    else        outr[i * 67 + (c - 67)] = v;
}

__global__ __launch_bounds__(256) void maskout_kernel(
    const float* __restrict__ pk, const float* __restrict__ mf,
    float* __restrict__ outm)
{
    const int b = blockIdx.x;
    const int lc = blockIdx.y;
    const int tid = threadIdx.x;
    __shared__ float pks[NINST][KD];
    for (int i = tid; i < NINST * KD; i += 256) pks[i >> 7][i & 127] = pk[b * NINST * KD + i];
    __syncthreads();
    const int l = lc * 256 + tid;
    if (l >= HW) return;
    float acc[NINST] = {};
    for (int k = 0; k < KD; ++k) {
        const float mv = mf[(b * KD + k) * HW + l];
        #pragma unroll
        for (int n = 0; n < NINST; ++n) acc[n] = fmaf(pks[n][k], mv, acc[n]);
    }
    #pragma unroll
    for (int n = 0; n < NINST; ++n)
        outm[(b * NINST + n) * HW + l] = acc[n];
}

// ---------------------------------------------------------------------------
extern "C" void kernel_launch(void* const* d_in, const int* in_sizes, int n_in,
                              void* d_out, int out_size, void* d_ws, size_t ws_size,
                              hipStream_t stream)
{
    const float* features = (const float*)d_in[0];
    const float* iw0 = (const float*)d_in[1];
    const float* ib0 = (const float*)d_in[2];
    const float* iw1 = (const float*)d_in[3];
    const float* ib1 = (const float*)d_in[4];
    const float* iw2 = (const float*)d_in[5];
    const float* ib2 = (const float*)d_in[6];
    const float* iw3 = (const float*)d_in[7];
    const float* ib3 = (const float*)d_in[8];
    const float* iam_w = (const float*)d_in[9];
    const float* iam_b = (const float*)d_in[10];
    const float* cls_w = (const float*)d_in[11];
    const float* cls_b = (const float*)d_in[12];
    const float* mk_w = (const float*)d_in[13];
    const float* mk_b = (const float*)d_in[14];
    const float* mw0 = (const float*)d_in[15];
    const float* mb0 = (const float*)d_in[16];
    const float* mw1 = (const float*)d_in[17];
    const float* mb1 = (const float*)d_in[18];
    const float* mw2 = (const float*)d_in[19];
    const float* mb2 = (const float*)d_in[20];
    const float* mw3 = (const float*)d_in[21];
    const float* mb3 = (const float*)d_in[22];
    const float* pw = (const float*)d_in[23];
    const float* pb = (const float*)d_in[24];

    char* ws = (char*)d_ws;
    size_t off = 0;
    auto nextUS = [&](size_t elems) {
        unsigned short* p = (unsigned short*)(ws + off);
        off = (off + elems * 2 + 255) & ~(size_t)255;
        return p;
    };
    // repacked weights (hi + optional lo)
    unsigned short* wpi0h = nextUS(134 * 9 * 288);
    unsigned short* wpi0l = nextUS(134 * 9 * 288);
    unsigned short* wpi1h = nextUS(134 * 9 * 160);
    unsigned short* wpi1l = nextUS(134 * 9 * 160);
    unsigned short* wpi2h = nextUS(134 * 9 * 160);
    unsigned short* wpi2l = nextUS(134 * 9 * 160);
    unsigned short* wpi3h = nextUS(134 * 9 * 160);
    unsigned short* wpi3l = nextUS(134 * 9 * 160);
    unsigned short* wpm0h = nextUS(256 * 9 * 288);
    unsigned short* wpm1h = nextUS(256 * 9 * 256);
    unsigned short* wpm2h = nextUS(256 * 9 * 256);
    unsigned short* wpm3h = nextUS(256 * 9 * 256);
    unsigned short* wppjh = nextUS(128 * 256);

    float* RA = (float*)(ws + off); off += 34304000;   // 16*134*4000 f32 (also holds 16*256*4000 bf16 / 16*128*4000 f32)
    float* RB = (float*)(ws + off); off += 34304000;
    float* iamb = (float*)(ws + off); off += 1024000;
    int*   pos   = (int*)(ws + off); off += 256;
    float* denom = (float*)(ws + off); off += 256;
    float* instb = (float*)(ws + off); off += 34304;
    off = (off + 255) & ~(size_t)255;
    float* pk = (float*)(ws + off); off += 32768;

    float* out_logits = (float*)d_out;              // 64*2
    float* out_mask   = out_logits + 64 * NCLS;     // 64*67
    float* out_reg    = out_mask + 64 * 67;         // 64*67
    float* out_masks  = out_reg + 64 * 67;          // 64*4000

    const dim3 blk(256);
    auto rp = [&](const float* W, unsigned short* h, unsigned short* l,
                  int Cout_, int Cin_, int RS_, int Cpad_, int dolo) {
        const int tot = RS_ * Cout_ * Cpad_;
        repack_w<<<dim3((tot + 255) / 256), blk, 0, stream>>>(W, h, l, Cout_, Cin_, RS_, Cpad_, dolo);
    };
    rp(iw0, wpi0h, wpi0l, 134, 258, 9, 288, 1);
    rp(iw1, wpi1h, wpi1l, 134, 134, 9, 160, 1);
    rp(iw2, wpi2h, wpi2l, 134, 134, 9, 160, 1);
    rp(iw3, wpi3h, wpi3l, 134, 134, 9, 160, 1);
    rp(mw0, wpm0h, nullptr, 256, 258, 9, 288, 0);
    rp(mw1, wpm1h, nullptr, 256, 256, 9, 256, 0);
    rp(mw2, wpm2h, nullptr, 256, 256, 9, 256, 0);
    rp(mw3, wpm3h, nullptr, 256, 256, 9, 256, 0);
    rp(pw,  wppjh, nullptr, 128, 256, 1, 256, 0);

    // ---- inst branch: fp32 in/out, SPLIT=3 (argmax-safe), BN=64 ----
    conv_mfma<1, 3, 64, 0, 0><<<dim3(3, 500), blk, 0, stream>>>(features, wpi0h, wpi0l, ib0, RA, 258, DIM, 1);
    conv_mfma<0, 3, 64, 0, 0><<<dim3(3, 500), blk, 0, stream>>>(RA, wpi1h, wpi1l, ib1, RB, DIM, DIM, 1);
    conv_mfma<0, 3, 64, 0, 0><<<dim3(3, 500), blk, 0, stream>>>(RB, wpi2h, wpi2l, ib2, RA, DIM, DIM, 1);
    conv_mfma<0, 3, 64, 0, 0><<<dim3(3, 500), blk, 0, stream>>>(RA, wpi3h, wpi3l, ib3, RB, DIM, DIM, 1);

    iam_conv<<<dim3(250), blk, 0, stream>>>(RB, iam_w, iam_b, iamb);
    stats_kernel<<<dim3(64), blk, 0, stream>>>(iamb, pos, denom);
    inst_kernel<<<dim3(16, DIM), blk, 0, stream>>>(iamb, RB, denom, instb);
    head_kernel<<<dim3(64), dim3(128), 0, stream>>>(instb, cls_w, cls_b, mk_w, mk_b, out_logits, pk);
    gather_kernel<<<dim3(64), dim3(192), 0, stream>>>(RB, pos, out_mask, out_reg);

    // ---- mask branch: bf16 intermediates, SPLIT=1, BN=128 ----
    unsigned short* RAb = (unsigned short*)RA;
    unsigned short* RBb = (unsigned short*)RB;
    conv_mfma<1, 1, 128, 0, 1><<<dim3(2, 500), blk, 0, stream>>>(features, wpm0h, nullptr, mb0, RAb, 258, MDIM, 1);
    conv_mfma<0, 1, 128, 1, 1><<<dim3(2, 500), blk, 0, stream>>>(RAb, wpm1h, nullptr, mb1, RBb, MDIM, MDIM, 1);
    conv_mfma<0, 1, 128, 1, 1><<<dim3(2, 500), blk, 0, stream>>>(RBb, wpm2h, nullptr, mb2, RAb, MDIM, MDIM, 1);
    conv_mfma<0, 1, 128, 1, 1><<<dim3(2, 500), blk, 0, stream>>>(RAb, wpm3h, nullptr, mb3, RBb, MDIM, MDIM, 1);
    conv_mfma<2, 1, 128, 1, 0><<<dim3(1, 500), blk, 0, stream>>>(RBb, wppjh, nullptr, pb, RA, MDIM, KD, 0);

    maskout_kernel<<<dim3(16, 16), blk, 0, stream>>>(pk, RA, out_masks);
}

// Round 3
// 1665.221 us; speedup vs baseline: 6.5119x; 2.8612x over previous
//
#include <hip/hip_runtime.h>
#include <hip/hip_bf16.h>
#include <math.h>

constexpr int HW = 4000;
constexpr int HP = 4284;           // haloed pixels per image (42*102)
constexpr int NPIXH = 16 * HP;     // 68544

typedef short s16x8 __attribute__((ext_vector_type(8)));
typedef float f32x4 __attribute__((ext_vector_type(4)));
typedef unsigned short u16x4 __attribute__((ext_vector_type(4)));
typedef unsigned short u16;

__device__ __forceinline__ u16 f2bf(float f) {
    __hip_bfloat16 h = __float2bfloat16(f);
    u16 b; __builtin_memcpy(&b, &h, 2); return b;
}
__device__ __forceinline__ float bf2f(u16 b) {
    __hip_bfloat16 h; __builtin_memcpy(&h, &b, 2); return __bfloat162float(h);
}

__device__ __forceinline__ void gload_lds16(const void* g, void* l) {
    __builtin_amdgcn_global_load_lds(
        (const __attribute__((address_space(1))) void*)g,
        (__attribute__((address_space(3))) void*)l, 16, 0, 0);
}

// ---------------------------------------------------------------------------
// Weight repack: OIHW fp32 -> fragment-ordered LDS image, bf16 hi (+ lo).
// chunk q within (rs,ch): f=q>>6,g=(q>>4)&3,r=q&15 -> n=f*16+r, c=ch*32+g*8+j
// ---------------------------------------------------------------------------
__global__ __launch_bounds__(256) void repack_w(
    const float* __restrict__ W, u16* __restrict__ Wh, u16* __restrict__ Wl,
    int Cout, int Cin, int NRS, int nCh, int Npad, int do_lo)
{
    const int chunk = blockIdx.x * 256 + threadIdx.x;
    const int per = Npad * 4;
    const int total = NRS * nCh * per;
    if (chunk >= total) return;
    const int q = chunk % per;
    const int t2 = chunk / per;
    const int ch = t2 % nCh;
    const int rs = t2 / nCh;
    const int f = q >> 6, g = (q >> 4) & 3, rA = q & 15;
    const int n = f * 16 + rA;
    u16x4 hp[2], lp[2];
    #pragma unroll
    for (int j = 0; j < 8; ++j) {
        const int c = ch * 32 + g * 8 + j;
        const float v = (n < Cout && c < Cin) ? W[((size_t)n * Cin + c) * NRS + rs] : 0.f;
        const u16 hb = f2bf(v);
        hp[j >> 2][j & 3] = hb;
        lp[j >> 2][j & 3] = f2bf(v - bf2f(hb));
    }
    const size_t o = (size_t)chunk * 8;
    *(u16x4*)(Wh + o) = hp[0]; *(u16x4*)(Wh + o + 4) = hp[1];
    if (do_lo) { *(u16x4*)(Wl + o) = lp[0]; *(u16x4*)(Wl + o + 4) = lp[1]; }
}

// ---------------------------------------------------------------------------
// features NCHW fp32 -> haloed NHWC bf16 hi+lo, channels: 0=x,1=y,2..257=f,.. 0
// ---------------------------------------------------------------------------
__global__ __launch_bounds__(256) void prep_x0(
    const float* __restrict__ feat, u16* __restrict__ Xh, u16* __restrict__ Xl)
{
    const int p = blockIdx.x * 256 + threadIdx.x;
    if (p >= NPIXH) return;
    const int b = p / HP; const int rem = p - b * HP;
    const int hh = rem / 102, wp = rem - hh * 102;
    const bool halo = (hh == 0) | (hh == 41) | (wp == 0) | (wp == 101);
    const int h = hh - 1, w = wp - 1;
    const int hw = h * 100 + w;
    const float xw = -1.f + 2.f * (float)w / 99.f;
    const float yh = -1.f + 2.f * (float)h / 39.f;
    for (int cg = 0; cg < 36; ++cg) {
        u16x4 hp[2], lp[2];
        #pragma unroll
        for (int j = 0; j < 8; ++j) {
            const int c = cg * 8 + j;
            float v = 0.f;
            if (!halo) {
                if (c == 0) v = xw;
                else if (c == 1) v = yh;
                else if (c < 258) v = feat[((size_t)(b * 256 + (c - 2))) * HW + hw];
            }
            const u16 hb = f2bf(v);
            hp[j >> 2][j & 3] = hb;
            lp[j >> 2][j & 3] = f2bf(v - bf2f(hb));
        }
        const size_t o = (size_t)p * 288 + cg * 8;
        *(u16x4*)(Xh + o) = hp[0]; *(u16x4*)(Xh + o + 4) = hp[1];
        *(u16x4*)(Xl + o) = lp[0]; *(u16x4*)(Xl + o + 4) = lp[1];
    }
}

// zero the halo ring of up to 4 NHWC planes
__global__ __launch_bounds__(256) void zero_halo(
    u16* p0, u16* p1, u16* p2, u16* p3, int Cpad)
{
    const int p = blockIdx.x * 256 + threadIdx.x;
    if (p >= NPIXH) return;
    const int rem = p % HP;
    const int hh = rem / 102, wp = rem - hh * 102;
    if (!((hh == 0) | (hh == 41) | (wp == 0) | (wp == 101))) return;
    const u16x4 z = {0, 0, 0, 0};
    for (int i = 0; i < Cpad; i += 4) {
        const size_t o = (size_t)p * Cpad + i;
        if (p0) *(u16x4*)(p0 + o) = z;
        if (p1) *(u16x4*)(p1 + o) = z;
        if (p2) *(u16x4*)(p2 + o) = z;
        if (p3) *(u16x4*)(p3 + o) = z;
    }
}

// ---------------------------------------------------------------------------
// bf16-MFMA implicit-GEMM conv on haloed NHWC input.
// mfma(A=weights, B=pixels): acc rows = channels (4 consec per lane), cols = m.
// BM=128 pixels, BK=32 channels, BN template. 2-phase dbuf + global_load_lds.
// SPLIT 1: hi only. SPLIT 3: hi+lo (ah*bh + ah*bl + al*bh).
// OUTMODE 0: haloed NHWC bf16 hi+lo; 1: haloed NHWC bf16 hi; 2: compact NHWC f32
// ---------------------------------------------------------------------------
template <int SPLIT, int BN, int NRS, int OUTMODE>
__global__ __launch_bounds__(256) void conv_mfma(
    const u16* __restrict__ Xhi, const u16* __restrict__ Xlo,
    const u16* __restrict__ Whi, const u16* __restrict__ Wlo,
    const float* __restrict__ bias,
    u16* __restrict__ Yhi, u16* __restrict__ Ylo, float* __restrict__ Yf,
    int CpadIn, int nCh, int Npad, int Cout, int CoutStore, int CpadOut, int do_relu)
{
    constexpr int FA = BN / 32;          // n-frags per wave
    constexpr int NIW = (BN * 4) / 256;  // W staging issues (1 or 2)

    __shared__ u16 lsXh[2][4096];
    __shared__ u16 lsXl[SPLIT == 3 ? 2 : 1][SPLIT == 3 ? 4096 : 8];
    __shared__ u16 lsWh[2][BN * 32];
    __shared__ u16 lsWl[SPLIT == 3 ? 2 : 1][SPLIT == 3 ? BN * 32 : 8];

    const int tid = threadIdx.x;
    const int m0 = blockIdx.y * 128;
    const int n0 = blockIdx.x * BN;

    // X staging precompute: thread covers chunks q=tid and tid+256
    int pB[2], cO[2], xdst[2];
    #pragma unroll
    for (int q2 = 0; q2 < 2; ++q2) {
        const int q = tid + q2 * 256;
        const int f = q >> 6, g = (q >> 4) & 3, rL = q & 15;
        const int m = m0 + f * 16 + rL;
        const int b = m / HW; const int hw = m - b * HW;
        const int h = hw / 100, w = hw - h * 100;
        pB[q2] = b * HP + h * 102 + w;
        cO[q2] = g * 8;
        xdst[q2] = (q & ~63) * 16;
    }
    const int wbase = (n0 >> 4) * 64;

    auto stage = [&](int step, int bsel) {
        const int ch = step / NRS;
        const int rs = step - ch * NRS;
        const int tap = (NRS == 9) ? ((rs / 3) * 102 + (rs % 3)) : 103;
        const int c0 = ch * 32;
        #pragma unroll
        for (int q2 = 0; q2 < 2; ++q2) {
            const size_t gi = (size_t)(pB[q2] + tap) * CpadIn + c0 + cO[q2];
            gload_lds16(Xhi + gi, (char*)&lsXh[bsel][0] + xdst[q2]);
            if constexpr (SPLIT == 3)
                gload_lds16(Xlo + gi, (char*)&lsXl[bsel][0] + xdst[q2]);
        }
        const int wb = (rs * nCh + ch) * (Npad * 4) + wbase;
        #pragma unroll
        for (int i = 0; i < NIW; ++i) {
            const int q = tid + i * 256;
            const size_t gi = (size_t)(wb + q) * 8;
            const int d = (q & ~63) * 16;
            gload_lds16(Whi + gi, (char*)&lsWh[bsel][0] + d);
            if constexpr (SPLIT == 3)
                gload_lds16(Wlo + gi, (char*)&lsWl[bsel][0] + d);
        }
    };

    const int T = nCh * NRS;
    stage(0, 0);
    __syncthreads();

    const int lane = tid & 63, wid = tid >> 6;
    const int wn = (wid & 1) * (BN / 2);
    const int wm = (wid >> 1) * 64;
    const int gA = lane >> 4, rA = lane & 15;

    f32x4 acc[FA][4];
    #pragma unroll
    for (int i = 0; i < FA; ++i)
        #pragma unroll
        for (int j = 0; j < 4; ++j) acc[i][j] = (f32x4){0.f, 0.f, 0.f, 0.f};

    for (int t = 0; t < T; ++t) {
        const int cur = t & 1;
        if (t + 1 < T) stage(t + 1, cur ^ 1);

        s16x8 aW[FA], bX[4];
        s16x8 aWl[SPLIT == 3 ? FA : 1], bXl[SPLIT == 3 ? 4 : 1];
        #pragma unroll
        for (int fa = 0; fa < FA; ++fa) {
            const int idx = ((((wn >> 4) + fa) * 64) + gA * 16 + rA) * 8;
            aW[fa] = *(const s16x8*)&lsWh[cur][idx];
            if constexpr (SPLIT == 3) aWl[fa] = *(const s16x8*)&lsWl[cur][idx];
        }
        #pragma unroll
        for (int fb = 0; fb < 4; ++fb) {
            const int idx = ((((wm >> 4) + fb) * 64) + gA * 16 + rA) * 8;
            bX[fb] = *(const s16x8*)&lsXh[cur][idx];
            if constexpr (SPLIT == 3) bXl[fb] = *(const s16x8*)&lsXl[cur][idx];
        }
        #pragma unroll
        for (int fa = 0; fa < FA; ++fa)
            #pragma unroll
            for (int fb = 0; fb < 4; ++fb) {
                acc[fa][fb] = __builtin_amdgcn_mfma_f32_16x16x32_bf16(
                    aW[fa], bX[fb], acc[fa][fb], 0, 0, 0);
                if constexpr (SPLIT == 3) {
                    acc[fa][fb] = __builtin_amdgcn_mfma_f32_16x16x32_bf16(
                        aW[fa], bXl[fb], acc[fa][fb], 0, 0, 0);
                    acc[fa][fb] = __builtin_amdgcn_mfma_f32_16x16x32_bf16(
                        aWl[fa], bX[fb], acc[fa][fb], 0, 0, 0);
                }
            }
        __syncthreads();
    }

    // epilogue
    const int mcol = lane & 15;
    const int nrow = (lane >> 4) * 4;
    #pragma unroll
    for (int fb = 0; fb < 4; ++fb) {
        const int m = m0 + wm + fb * 16 + mcol;
        const int b = m / HW; const int hw = m - b * HW;
        const int h = hw / 100, w = hw - h * 100;
        size_t obase;
        if constexpr (OUTMODE == 2) obase = (size_t)m * CpadOut;
        else obase = (size_t)(b * HP + (h + 1) * 102 + (w + 1)) * CpadOut;
        #pragma unroll
        for (int fa = 0; fa < FA; ++fa) {
            const int nb = n0 + wn + fa * 16 + nrow;
            if (nb >= CoutStore) continue;
            f32x4 v = acc[fa][fb];
            #pragma unroll
            for (int i = 0; i < 4; ++i) {
                const int n = nb + i;
                float x = (n < Cout) ? (v[i] + bias[n]) : 0.f;
                if (do_relu) x = fmaxf(x, 0.f);
                v[i] = x;
            }
            if constexpr (OUTMODE == 2) {
                *(f32x4*)(Yf + obase + nb) = v;
            } else {
                u16x4 hp;
                #pragma unroll
                for (int i = 0; i < 4; ++i) hp[i] = f2bf(v[i]);
                *(u16x4*)(Yhi + obase + nb) = hp;
                if constexpr (OUTMODE == 0) {
                    u16x4 lp;
                    #pragma unroll
                    for (int i = 0; i < 4; ++i) lp[i] = f2bf(v[i] - bf2f(hp[i]));
                    *(u16x4*)(Ylo + obase + nb) = lp;
                }
            }
        }
    }
}

// ---------------------------------------------------------------------------
// iam conv: 4 outputs, 3x3, consumes haloed NHWC hi+lo (fp32-equivalent)
// ---------------------------------------------------------------------------
__global__ __launch_bounds__(256) void iam_conv_nhwc(
    const u16* __restrict__ fhi, const u16* __restrict__ flo,
    const float* __restrict__ Wt, const float* __restrict__ bias,
    float* __restrict__ iam)
{
    __shared__ float wsm[9 * 134 * 4];
    const int tid = threadIdx.x;
    for (int i = tid; i < 4824; i += 256) {
        const int rs = i / 536; const int rem = i - rs * 536;
        const int c = rem >> 2; const int n = rem & 3;
        wsm[i] = Wt[(n * 134 + c) * 9 + rs];
    }
    __syncthreads();
    const int m = blockIdx.x * 256 + tid;
    const int b = m / HW; const int hw = m - b * HW;
    const int h = hw / 100, w = hw - h * 100;
    const int pB = b * HP + h * 102 + w;
    float a0 = bias[0], a1 = bias[1], a2 = bias[2], a3 = bias[3];
    for (int rs = 0; rs < 9; ++rs) {
        const size_t p = (size_t)(pB + (rs / 3) * 102 + (rs % 3)) * 160;
        const float* wrow = &wsm[rs * 536];
        for (int cg = 0; cg < 17; ++cg) {
            s16x8 hv = *(const s16x8*)(fhi + p + cg * 8);
            s16x8 lv = *(const s16x8*)(flo + p + cg * 8);
            #pragma unroll
            for (int j = 0; j < 8; ++j) {
                const int c = cg * 8 + j;
                if (c < 134) {
                    const float v = bf2f((u16)hv[j]) + bf2f((u16)lv[j]);
                    const float* wc = wrow + c * 4;
                    a0 = fmaf(v, wc[0], a0); a1 = fmaf(v, wc[1], a1);
                    a2 = fmaf(v, wc[2], a2); a3 = fmaf(v, wc[3], a3);
                }
            }
        }
    }
    iam[(b * 4 + 0) * HW + hw] = a0;
    iam[(b * 4 + 1) * HW + hw] = a1;
    iam[(b * 4 + 2) * HW + hw] = a2;
    iam[(b * 4 + 3) * HW + hw] = a3;
}

__device__ __forceinline__ float sigmoidf_dev(float x) {
    return 1.f / (1.f + expf(-x));
}

__global__ __launch_bounds__(256) void stats_kernel(
    const float* __restrict__ iam, int* __restrict__ pos, float* __restrict__ denom)
{
    const int i = blockIdx.x;
    const int tid = threadIdx.x;
    const float* p = &iam[i * HW];
    float bm = -1e30f; int bi = 0; float sum = 0.f;
    for (int l = tid; l < HW; l += 256) {
        const float s = sigmoidf_dev(p[l]);
        sum += s;
        if (s > bm) { bm = s; bi = l; }
    }
    __shared__ float sm[256]; __shared__ int si[256]; __shared__ float ss[256];
    sm[tid] = bm; si[tid] = bi; ss[tid] = sum;
    __syncthreads();
    for (int off = 128; off > 0; off >>= 1) {
        if (tid < off) {
            ss[tid] += ss[tid + off];
            const float m2 = sm[tid + off]; const int i2 = si[tid + off];
            if (m2 > sm[tid] || (m2 == sm[tid] && i2 < si[tid])) { sm[tid] = m2; si[tid] = i2; }
        }
        __syncthreads();
    }
    if (tid == 0) { pos[i] = si[0]; denom[i] = fmaxf(ss[0], 1e-6f); }
}

// inst[b][n][c] = sum_l sig(iam) * f / denom ; f from haloed NHWC hi+lo
__global__ __launch_bounds__(256) void inst_nhwc(
    const u16* __restrict__ fhi, const u16* __restrict__ flo,
    const float* __restrict__ iam, const float* __restrict__ denom,
    float* __restrict__ inst)
{
    const int b = blockIdx.x, cg = blockIdx.y;   // cg < 17
    const int tid = threadIdx.x;
    float acc[4][8] = {};
    for (int l = tid; l < HW; l += 256) {
        const int p = b * HP + (l / 100 + 1) * 102 + (l % 100) + 1;
        s16x8 hv = *(const s16x8*)(fhi + (size_t)p * 160 + cg * 8);
        s16x8 lv = *(const s16x8*)(flo + (size_t)p * 160 + cg * 8);
        float fv[8];
        #pragma unroll
        for (int j = 0; j < 8; ++j) fv[j] = bf2f((u16)hv[j]) + bf2f((u16)lv[j]);
        #pragma unroll
        for (int n = 0; n < 4; ++n) {
            const float s = sigmoidf_dev(iam[(b * 4 + n) * HW + l]);
            #pragma unroll
            for (int j = 0; j < 8; ++j) acc[n][j] = fmaf(s, fv[j], acc[n][j]);
        }
    }
    __shared__ float red[128];
    const int lane = tid & 63, wid = tid >> 6;
    #pragma unroll
    for (int n = 0; n < 4; ++n)
        #pragma unroll
        for (int j = 0; j < 8; ++j) {
            float v = acc[n][j];
            #pragma unroll
            for (int off = 32; off > 0; off >>= 1) v += __shfl_xor(v, off);
            if (lane == 0) red[wid * 32 + n * 8 + j] = v;
        }
    __syncthreads();
    if (tid < 32) {
        const float s = red[tid] + red[32 + tid] + red[64 + tid] + red[96 + tid];
        const int n = tid >> 3, j = tid & 7;
        const int c = cg * 8 + j;
        if (c < 134) inst[(b * 4 + n) * 134 + c] = s / denom[b * 4 + n];
    }
}

__global__ __launch_bounds__(128) void head_kernel(
    const float* __restrict__ inst,
    const float* __restrict__ cls_w, const float* __restrict__ cls_b,
    const float* __restrict__ mk_w, const float* __restrict__ mk_b,
    float* __restrict__ out_logits, float* __restrict__ pk)
{
    const int i = blockIdx.x;
    const int tid = threadIdx.x;
    __shared__ float iv[134];
    for (int c = tid; c < 134; c += 128) iv[c] = inst[i * 134 + c];
    __syncthreads();
    float a = mk_b[tid];
    for (int c = 0; c < 134; ++c) a = fmaf(iv[c], mk_w[tid * 134 + c], a);
    pk[i * 128 + tid] = a;
    if (tid < 2) {
        float g = cls_b[tid];
        for (int c = 0; c < 134; ++c) g = fmaf(iv[c], cls_w[tid * 134 + c], g);
        out_logits[i * 2 + tid] = g;
    }
}

__global__ void gather_nhwc(
    const u16* __restrict__ fhi, const u16* __restrict__ flo,
    const int* __restrict__ pos, float* __restrict__ outm, float* __restrict__ outr)
{
    const int i = blockIdx.x;
    const int c = threadIdx.x;
    if (c >= 134) return;
    const int p = pos[i];                          // batch-0 quirk preserved
    const int ph = (p / 100 + 1) * 102 + (p % 100) + 1;
    const float v = bf2f(fhi[(size_t)ph * 160 + c]) + bf2f(flo[(size_t)ph * 160 + c]);
    if (c < 67) outm[i * 67 + c] = v;
    else        outr[i * 67 + (c - 67)] = v;
}

// pred_masks from compact NHWC mf [m][128] f32
__global__ __launch_bounds__(256) void maskout_nhwc(
    const float* __restrict__ pk, const float* __restrict__ mf,
    float* __restrict__ outm)
{
    const int b = blockIdx.x, lc = blockIdx.y;
    const int tid = threadIdx.x;
    __shared__ float pks[4][128];
    for (int i = tid; i < 512; i += 256) pks[i >> 7][i & 127] = pk[b * 512 + i];
    __syncthreads();
    const int l = lc * 256 + tid;
    if (l >= HW) return;
    const float* row = mf + (size_t)(b * HW + l) * 128;
    float a[4] = {};
    for (int k = 0; k < 128; k += 4) {
        const f32x4 mv = *(const f32x4*)(row + k);
        #pragma unroll
        for (int n = 0; n < 4; ++n) {
            a[n] = fmaf(pks[n][k + 0], mv[0], a[n]);
            a[n] = fmaf(pks[n][k + 1], mv[1], a[n]);
            a[n] = fmaf(pks[n][k + 2], mv[2], a[n]);
            a[n] = fmaf(pks[n][k + 3], mv[3], a[n]);
        }
    }
    #pragma unroll
    for (int n = 0; n < 4; ++n) outm[(b * 4 + n) * HW + l] = a[n];
}

// ---------------------------------------------------------------------------
extern "C" void kernel_launch(void* const* d_in, const int* in_sizes, int n_in,
                              void* d_out, int out_size, void* d_ws, size_t ws_size,
                              hipStream_t stream)
{
    const float* features = (const float*)d_in[0];
    const float* iw0 = (const float*)d_in[1];
    const float* ib0 = (const float*)d_in[2];
    const float* iw1 = (const float*)d_in[3];
    const float* ib1 = (const float*)d_in[4];
    const float* iw2 = (const float*)d_in[5];
    const float* ib2 = (const float*)d_in[6];
    const float* iw3 = (const float*)d_in[7];
    const float* ib3 = (const float*)d_in[8];
    const float* iam_w = (const float*)d_in[9];
    const float* iam_b = (const float*)d_in[10];
    const float* cls_w = (const float*)d_in[11];
    const float* cls_b = (const float*)d_in[12];
    const float* mk_w = (const float*)d_in[13];
    const float* mk_b = (const float*)d_in[14];
    const float* mw0 = (const float*)d_in[15];
    const float* mb0 = (const float*)d_in[16];
    const float* mw1 = (const float*)d_in[17];
    const float* mb1 = (const float*)d_in[18];
    const float* mw2 = (const float*)d_in[19];
    const float* mb2 = (const float*)d_in[20];
    const float* mw3 = (const float*)d_in[21];
    const float* mb3 = (const float*)d_in[22];
    const float* pw = (const float*)d_in[23];
    const float* pb = (const float*)d_in[24];

    // sizes (bytes)
    constexpr size_t WI0 = 995328, WI123 = 552960;
    constexpr size_t WM0 = 1327104, WM123 = 1179648, WPJ = 65536;
    constexpr size_t X0B = (size_t)NPIXH * 288 * 2;       // 39,481,344
    constexpr size_t P160 = (size_t)NPIXH * 160 * 2;      // 21,934,080
    constexpr size_t REGION = 2 * P160;                   // 43,868,160

    char* ws = (char*)d_ws;
    size_t off = 0;
    auto carve = [&](size_t bytes) { char* p = ws + off; off += bytes; return p; };
    u16* wi0h = (u16*)carve(WI0); u16* wi0l = (u16*)carve(WI0);
    u16* wi1h = (u16*)carve(WI123); u16* wi1l = (u16*)carve(WI123);
    u16* wi2h = (u16*)carve(WI123); u16* wi2l = (u16*)carve(WI123);
    u16* wi3h = (u16*)carve(WI123); u16* wi3l = (u16*)carve(WI123);
    u16* wm0h = (u16*)carve(WM0);
    u16* wm1h = (u16*)carve(WM123); u16* wm2h = (u16*)carve(WM123); u16* wm3h = (u16*)carve(WM123);
    u16* wpjh = (u16*)carve(WPJ);
    u16* X0hi = (u16*)carve(X0B);
    char* R1 = carve(REGION);   // X0lo -> {RBhi,RBlo} -> MAhi -> mf
    char* R2 = carve(REGION);   // {RAhi,RAlo} -> MBhi
    float* iamb = (float*)carve(1024000);
    int* pos = (int*)carve(256);
    float* denom = (float*)carve(256);
    float* instb = (float*)carve(34560);
    float* pkbuf = (float*)carve(32768);

    u16* X0lo = (u16*)R1;
    u16* RBhi = (u16*)R1; u16* RBlo = (u16*)(R1 + P160);
    u16* MAhi = (u16*)R1;
    float* mf = (float*)R1;
    u16* RAhi = (u16*)R2; u16* RAlo = (u16*)(R2 + P160);
    u16* MBhi = (u16*)R2;

    float* out_logits = (float*)d_out;          // 64*2
    float* out_mask = out_logits + 128;         // 64*67
    float* out_reg = out_mask + 64 * 67;        // 64*67
    float* out_masks = out_reg + 64 * 67;       // 64*4000

    const dim3 blk(256);
    auto rp = [&](const float* W, u16* h, u16* l, int Cout_, int Cin_, int NRS_,
                  int nCh_, int Npad_, int dolo) {
        const int tot = NRS_ * nCh_ * Npad_ * 4;
        repack_w<<<dim3((tot + 255) / 256), blk, 0, stream>>>(W, h, l, Cout_, Cin_, NRS_, nCh_, Npad_, dolo);
    };
    rp(iw0, wi0h, wi0l, 134, 258, 9, 9, 192, 1);
    rp(iw1, wi1h, wi1l, 134, 134, 9, 5, 192, 1);
    rp(iw2, wi2h, wi2l, 134, 134, 9, 5, 192, 1);
    rp(iw3, wi3h, wi3l, 134, 134, 9, 5, 192, 1);
    rp(mw0, wm0h, nullptr, 256, 258, 9, 9, 256, 0);
    rp(mw1, wm1h, nullptr, 256, 256, 9, 8, 256, 0);
    rp(mw2, wm2h, nullptr, 256, 256, 9, 8, 256, 0);
    rp(mw3, wm3h, nullptr, 256, 256, 1, 8, 256, 0);   // NOTE: fixed below
    rp(pw, wpjh, nullptr, 128, 256, 1, 8, 128, 0);

    // (mw3 repack above must be 3x3: relaunch with correct params — keep single
    // correct call; the erroneous one is overwritten)
    rp(mw3, wm3h, nullptr, 256, 256, 9, 8, 256, 0);

    const dim3 gH((NPIXH + 255) / 256);
    prep_x0<<<gH, blk, 0, stream>>>(features, X0hi, X0lo);
    zero_halo<<<gH, blk, 0, stream>>>(RAhi, RAlo, nullptr, nullptr, 160);

    // ---- inst branch: SPLIT=3, BN=64, haloed bf16 hi+lo ----
    conv_mfma<3, 64, 9, 0><<<dim3(3, 500), blk, 0, stream>>>(
        X0hi, X0lo, wi0h, wi0l, ib0, RAhi, RAlo, nullptr, 288, 9, 192, 134, 160, 160, 1);
    zero_halo<<<gH, blk, 0, stream>>>(RBhi, RBlo, nullptr, nullptr, 160);
    conv_mfma<3, 64, 9, 0><<<dim3(3, 500), blk, 0, stream>>>(
        RAhi, RAlo, wi1h, wi1l, ib1, RBhi, RBlo, nullptr, 160, 5, 192, 134, 160, 160, 1);
    conv_mfma<3, 64, 9, 0><<<dim3(3, 500), blk, 0, stream>>>(
        RBhi, RBlo, wi2h, wi2l, ib2, RAhi, RAlo, nullptr, 160, 5, 192, 134, 160, 160, 1);
    conv_mfma<3, 64, 9, 0><<<dim3(3, 500), blk, 0, stream>>>(
        RAhi, RAlo, wi3h, wi3l, ib3, RBhi, RBlo, nullptr, 160, 5, 192, 134, 160, 160, 1);

    iam_conv_nhwc<<<dim3(250), blk, 0, stream>>>(RBhi, RBlo, iam_w, iam_b, iamb);
    stats_kernel<<<dim3(64), blk, 0, stream>>>(iamb, pos, denom);
    inst_nhwc<<<dim3(16, 17), blk, 0, stream>>>(RBhi, RBlo, iamb, denom, instb);
    head_kernel<<<dim3(64), dim3(128), 0, stream>>>(instb, cls_w, cls_b, mk_w, mk_b, out_logits, pkbuf);
    gather_nhwc<<<dim3(64), dim3(192), 0, stream>>>(RBhi, RBlo, pos, out_mask, out_reg);

    // ---- mask branch: SPLIT=1, BN=128, haloed bf16 hi ----
    zero_halo<<<gH, blk, 0, stream>>>(MAhi, MBhi, nullptr, nullptr, 256);
    conv_mfma<1, 128, 9, 1><<<dim3(2, 500), blk, 0, stream>>>(
        X0hi, nullptr, wm0h, nullptr, mb0, MAhi, nullptr, nullptr, 288, 9, 256, 256, 256, 256, 1);
    conv_mfma<1, 128, 9, 1><<<dim3(2, 500), blk, 0, stream>>>(
        MAhi, nullptr, wm1h, nullptr, mb1, MBhi, nullptr, nullptr, 256, 8, 256, 256, 256, 256, 1);
    conv_mfma<1, 128, 9, 1><<<dim3(2, 500), blk, 0, stream>>>(
        MBhi, nullptr, wm2h, nullptr, mb2, MAhi, nullptr, nullptr, 256, 8, 256, 256, 256, 256, 1);
    conv_mfma<1, 128, 9, 1><<<dim3(2, 500), blk, 0, stream>>>(
        MAhi, nullptr, wm3h, nullptr, mb3, MBhi, nullptr, nullptr, 256, 8, 256, 256, 256, 256, 1);
    conv_mfma<1, 128, 1, 2><<<dim3(1, 500), blk, 0, stream>>>(
        MBhi, nullptr, wpjh, nullptr, pb, nullptr, nullptr, mf, 256, 8, 128, 128, 128, 128, 0);

    maskout_nhwc<<<dim3(16, 16), blk, 0, stream>>>(pkbuf, mf, out_masks);
}

// Round 4
// 1268.093 us; speedup vs baseline: 8.5513x; 1.3132x over previous
//
#include <hip/hip_runtime.h>
#include <hip/hip_bf16.h>
#include <math.h>

constexpr int HW = 4000;
constexpr int HP = 4284;            // haloed pixels per image (42*102)
constexpr int HPAD = 4480;          // plane stride in pixels (incl. staging slack)
constexpr int NPIXH = 16 * HP;      // 68544

typedef short s16x8 __attribute__((ext_vector_type(8)));
typedef float f32x4 __attribute__((ext_vector_type(4)));
typedef unsigned short u16x4 __attribute__((ext_vector_type(4)));
typedef unsigned short u16;

__device__ __forceinline__ u16 f2bf(float f) {
    __hip_bfloat16 h = __float2bfloat16(f);
    u16 b; __builtin_memcpy(&b, &h, 2); return b;
}
__device__ __forceinline__ float bf2f(u16 b) {
    __hip_bfloat16 h; __builtin_memcpy(&h, &b, 2); return __bfloat162float(h);
}

__device__ __forceinline__ void gload_lds16(const void* g, void* l) {
    __builtin_amdgcn_global_load_lds(
        (const __attribute__((address_space(1))) void*)g,
        (__attribute__((address_space(3))) void*)l, 16, 0, 0);
}

// ---------------------------------------------------------------------------
// Weight repack: OIHW fp32 -> [rs][ch][Npad*4 chunks][8] bf16 hi (+ lo).
// chunk q: f=q>>6, g=(q>>4)&3, rA=q&15 -> n=f*16+rA, c=ch*32+g*8+j
// ---------------------------------------------------------------------------
__global__ __launch_bounds__(256) void repack_w(
    const float* __restrict__ W, u16* __restrict__ Wh, u16* __restrict__ Wl,
    int Cout, int Cin, int NRS, int nCh, int Npad, int do_lo)
{
    const int chunk = blockIdx.x * 256 + threadIdx.x;
    const int per = Npad * 4;
    const int total = NRS * nCh * per;
    if (chunk >= total) return;
    const int q = chunk % per;
    const int t2 = chunk / per;
    const int ch = t2 % nCh;
    const int rs = t2 / nCh;
    const int f = q >> 6, g = (q >> 4) & 3, rA = q & 15;
    const int n = f * 16 + rA;
    u16x4 hp[2], lp[2];
    #pragma unroll
    for (int j = 0; j < 8; ++j) {
        const int c = ch * 32 + g * 8 + j;
        const float v = (n < Cout && c < Cin) ? W[((size_t)n * Cin + c) * NRS + rs] : 0.f;
        const u16 hb = f2bf(v);
        hp[j >> 2][j & 3] = hb;
        lp[j >> 2][j & 3] = f2bf(v - bf2f(hb));
    }
    const size_t o = (size_t)chunk * 8;
    *(u16x4*)(Wh + o) = hp[0]; *(u16x4*)(Wh + o + 4) = hp[1];
    if (do_lo) { *(u16x4*)(Wl + o) = lp[0]; *(u16x4*)(Wl + o + 4) = lp[1]; }
}

// ---------------------------------------------------------------------------
// features NCHW fp32 -> planar-chunked haloed bf16 hi+lo (36 planes of 8 ch)
// channels: 0=x, 1=y, 2..257=f, 258..287=0
// ---------------------------------------------------------------------------
__global__ __launch_bounds__(256) void prep_x0(
    const float* __restrict__ feat, u16* __restrict__ Xh, u16* __restrict__ Xl)
{
    const int p = blockIdx.x * 256 + threadIdx.x;
    if (p >= NPIXH) return;
    const int b = p / HP; const int rem = p - b * HP;
    const int hh = rem / 102, wp = rem - hh * 102;
    const bool halo = (hh == 0) | (hh == 41) | (wp == 0) | (wp == 101);
    const int h = hh - 1, w = wp - 1;
    const int hw = h * 100 + w;
    const float xw = -1.f + 2.f * (float)w / 99.f;
    const float yh = -1.f + 2.f * (float)h / 39.f;
    for (int g = 0; g < 36; ++g) {
        u16x4 hp[2], lp[2];
        #pragma unroll
        for (int j = 0; j < 8; ++j) {
            const int c = g * 8 + j;
            float v = 0.f;
            if (!halo) {
                if (c == 0) v = xw;
                else if (c == 1) v = yh;
                else if (c < 258) v = feat[((size_t)(b * 256 + (c - 2))) * HW + hw];
            }
            const u16 hb = f2bf(v);
            hp[j >> 2][j & 3] = hb;
            lp[j >> 2][j & 3] = f2bf(v - bf2f(hb));
        }
        const size_t o = ((size_t)(b * 36 + g) * HPAD + rem) * 8;
        *(u16x4*)(Xh + o) = hp[0]; *(u16x4*)(Xh + o + 4) = hp[1];
        *(u16x4*)(Xl + o) = lp[0]; *(u16x4*)(Xl + o + 4) = lp[1];
    }
}

// zero the halo ring of two planar buffers
__global__ __launch_bounds__(256) void zero_halo_pl(
    u16* __restrict__ pa, u16* __restrict__ pb, int nGa, int nGb)
{
    const int p = blockIdx.x * 256 + threadIdx.x;
    if (p >= NPIXH) return;
    const int b = p / HP; const int rem = p - b * HP;
    const int hh = rem / 102, wp = rem - hh * 102;
    if (!((hh == 0) | (hh == 41) | (wp == 0) | (wp == 101))) return;
    const u16x4 z = {0, 0, 0, 0};
    for (int g = 0; g < nGa; ++g) {
        const size_t o = ((size_t)(b * nGa + g) * HPAD + rem) * 8;
        *(u16x4*)(pa + o) = z; *(u16x4*)(pa + o + 4) = z;
    }
    if (pb)
        for (int g = 0; g < nGb; ++g) {
            const size_t o = ((size_t)(b * nGb + g) * HPAD + rem) * 8;
            *(u16x4*)(pb + o) = z; *(u16x4*)(pb + o + 4) = z;
        }
}

// ---------------------------------------------------------------------------
// bf16-MFMA implicit-GEMM conv on planar-chunked haloed input, 9-tap LDS reuse.
// Per 32-ch chunk: stage 4 planes x 384 px once (global_load_lds), then all
// NRS taps read shifted windows from LDS. Weights double-buffered per tap.
// mfma(A=W, B=X): acc rows = channels (4/lane), cols = pixels.
// Grid: (nNblk, 32 m-blocks of 128 px, 16 images).
// SPLIT 1: hi only. SPLIT 3: hi+lo (3 passes, argmax-safe).
// OUTMODE 0: planar hi+lo; 1: planar hi; 2: compact [m][CoutStore] f32.
// ---------------------------------------------------------------------------
template <int SPLIT, int BN, int NRS, int OUTMODE>
__global__ __launch_bounds__(256) void conv_mfma(
    const u16* __restrict__ Xhi, const u16* __restrict__ Xlo,
    const u16* __restrict__ Whi, const u16* __restrict__ Wlo,
    const float* __restrict__ bias,
    u16* __restrict__ Yhi, u16* __restrict__ Ylo, float* __restrict__ Yf,
    int nCh, int Npad, int Cout, int CoutStore, int nGout, int do_relu)
{
    constexpr int FW = BN / 32;            // n-frags per wave
    constexpr int PS = 384;                // staged pixels per plane
    constexpr int NIW = (BN * 4) / 256;    // W staging issues per precision

    __shared__ u16 lsXh[4 * PS * 8];
    __shared__ u16 lsXl[SPLIT == 3 ? 4 * PS * 8 : 8];
    __shared__ u16 lsWh[2][BN * 32];
    __shared__ u16 lsWl[2][SPLIT == 3 ? BN * 32 : 8];

    const int tid = threadIdx.x, lane = tid & 63, wid = tid >> 6;
    const int b = blockIdx.z;
    const int off = blockIdx.y * 128;
    const int n0 = blockIdx.x * BN;
    const int nGin = nCh * 4;
    const int h0 = off / 100, w0 = off - h0 * 100;
    const int pTL0 = h0 * 102 + w0;

    const int wn = (wid & 1) * (BN / 2);
    const int wm = (wid >> 1) * 64;
    const int gA = lane >> 4, rA = lane & 15;

    // per-lane pixel displacement for the 4 m-frags
    int pd[4]; bool mval[4];
    #pragma unroll
    for (int fb = 0; fb < 4; ++fb) {
        int mm = off + wm + fb * 16 + rA;
        mval[fb] = mm < HW;
        if (!mval[fb]) mm = HW - 1;
        const int h = mm / 100, w = mm - h * 100;
        pd[fb] = (h * 102 + w) - pTL0;
    }

    auto stageX = [&](int ch) {
        const size_t src = ((size_t)(b * nGin + ch * 4 + wid) * HPAD + pTL0) * 8;
        const int dst = wid * PS * 8;    // u16
        #pragma unroll
        for (int i = 0; i < 6; ++i) {
            gload_lds16(Xhi + src + (size_t)(i * 64 + lane) * 8,
                        (char*)lsXh + (dst + i * 64 * 8) * 2);
            if constexpr (SPLIT == 3)
                gload_lds16(Xlo + src + (size_t)(i * 64 + lane) * 8,
                            (char*)lsXl + (dst + i * 64 * 8) * 2);
        }
    };
    auto stageW = [&](int ch, int rs, int buf) {
        const size_t wb = ((size_t)(rs * nCh + ch) * (Npad * 4) + (n0 >> 4) * 64) * 8;
        #pragma unroll
        for (int i = 0; i < NIW; ++i) {
            const int q = tid + i * 256;
            gload_lds16(Whi + wb + (size_t)q * 8, (char*)&lsWh[buf][0] + (q & ~63) * 16);
            if constexpr (SPLIT == 3)
                gload_lds16(Wlo + wb + (size_t)q * 8, (char*)&lsWl[buf][0] + (q & ~63) * 16);
        }
    };

    f32x4 acc[FW][4];
    #pragma unroll
    for (int i = 0; i < FW; ++i)
        #pragma unroll
        for (int j = 0; j < 4; ++j) acc[i][j] = (f32x4){0.f, 0.f, 0.f, 0.f};

    for (int ch = 0; ch < nCh; ++ch) {
        stageX(ch);
        stageW(ch, 0, 0);
        __syncthreads();
        for (int rs = 0; rs < NRS; ++rs) {
            if (rs + 1 < NRS) stageW(ch, rs + 1, (rs + 1) & 1);
            const int cb = rs & 1;
            const int toff = (NRS == 9) ? ((rs / 3) * 102 + (rs - 3 * (rs / 3))) : 103;

            s16x8 aW[FW], bX[4];
            s16x8 aWl[SPLIT == 3 ? FW : 1], bXl[SPLIT == 3 ? 4 : 1];
            #pragma unroll
            for (int fa = 0; fa < FW; ++fa) {
                const int idx = (((wn >> 4) + fa) * 64 + lane) * 8;
                aW[fa] = *(const s16x8*)&lsWh[cb][idx];
                if constexpr (SPLIT == 3) aWl[fa] = *(const s16x8*)&lsWl[cb][idx];
            }
            #pragma unroll
            for (int fb = 0; fb < 4; ++fb) {
                const int xi = (gA * PS + pd[fb] + toff) * 8;
                bX[fb] = *(const s16x8*)&lsXh[xi];
                if constexpr (SPLIT == 3) bXl[fb] = *(const s16x8*)&lsXl[xi];
            }
            #pragma unroll
            for (int fa = 0; fa < FW; ++fa)
                #pragma unroll
                for (int fb = 0; fb < 4; ++fb) {
                    acc[fa][fb] = __builtin_amdgcn_mfma_f32_16x16x32_bf16(
                        aW[fa], bX[fb], acc[fa][fb], 0, 0, 0);
                    if constexpr (SPLIT == 3) {
                        acc[fa][fb] = __builtin_amdgcn_mfma_f32_16x16x32_bf16(
                            aW[fa], bXl[fb], acc[fa][fb], 0, 0, 0);
                        acc[fa][fb] = __builtin_amdgcn_mfma_f32_16x16x32_bf16(
                            aWl[fa], bX[fb], acc[fa][fb], 0, 0, 0);
                    }
                }
            __syncthreads();
        }
    }

    // ---- epilogue ----
    #pragma unroll
    for (int fb = 0; fb < 4; ++fb) {
        if (!mval[fb]) continue;
        const int mm = off + wm + fb * 16 + rA;
        #pragma unroll
        for (int fa = 0; fa < FW; ++fa) {
            const int nb = n0 + wn + fa * 16 + gA * 4;
            if (nb >= CoutStore) continue;
            f32x4 v = acc[fa][fb];
            #pragma unroll
            for (int i = 0; i < 4; ++i) {
                const int n = nb + i;
                float x = (n < Cout) ? (v[i] + bias[n]) : 0.f;
                if (do_relu) x = fmaxf(x, 0.f);
                v[i] = x;
            }
            if constexpr (OUTMODE == 2) {
                *(f32x4*)(Yf + (size_t)(b * HW + mm) * CoutStore + nb) = v;
            } else {
                const size_t o =
                    ((size_t)(b * nGout + (nb >> 3)) * HPAD + pTL0 + pd[fb] + 103) * 8 + (nb & 7);
                u16x4 hp;
                #pragma unroll
                for (int i = 0; i < 4; ++i) hp[i] = f2bf(v[i]);
                *(u16x4*)(Yhi + o) = hp;
                if constexpr (OUTMODE == 0) {
                    u16x4 lp;
                    #pragma unroll
                    for (int i = 0; i < 4; ++i) lp[i] = f2bf(v[i] - bf2f(hp[i]));
                    *(u16x4*)(Ylo + o) = lp;
                }
            }
        }
    }
}

// ---------------------------------------------------------------------------
// iam conv: 4 outputs, 3x3, consumes planar hi+lo (fp32-equivalent), 20 planes
// ---------------------------------------------------------------------------
__global__ __launch_bounds__(256) void iam_conv_nhwc(
    const u16* __restrict__ fhi, const u16* __restrict__ flo,
    const float* __restrict__ Wt, const float* __restrict__ bias,
    float* __restrict__ iam)
{
    __shared__ float wsm[9 * 134 * 4];
    const int tid = threadIdx.x;
    for (int i = tid; i < 4824; i += 256) {
        const int rs = i / 536; const int rem = i - rs * 536;
        const int c = rem >> 2; const int n = rem & 3;
        wsm[i] = Wt[(n * 134 + c) * 9 + rs];
    }
    __syncthreads();
    const int m = blockIdx.x * 256 + tid;
    const int b = m / HW; const int hw = m - b * HW;
    const int h = hw / 100, w = hw - h * 100;
    const int pTL = h * 102 + w;
    float a0 = bias[0], a1 = bias[1], a2 = bias[2], a3 = bias[3];
    for (int rs = 0; rs < 9; ++rs) {
        const int pA = pTL + (rs / 3) * 102 + (rs % 3);
        const float* wrow = &wsm[rs * 536];
        for (int g = 0; g < 17; ++g) {
            const size_t o = ((size_t)(b * 20 + g) * HPAD + pA) * 8;
            s16x8 hv = *(const s16x8*)(fhi + o);
            s16x8 lv = *(const s16x8*)(flo + o);
            #pragma unroll
            for (int j = 0; j < 8; ++j) {
                const int c = g * 8 + j;
                if (c < 134) {
                    const float v = bf2f((u16)hv[j]) + bf2f((u16)lv[j]);
                    const float* wc = wrow + c * 4;
                    a0 = fmaf(v, wc[0], a0); a1 = fmaf(v, wc[1], a1);
                    a2 = fmaf(v, wc[2], a2); a3 = fmaf(v, wc[3], a3);
                }
            }
        }
    }
    iam[(b * 4 + 0) * HW + hw] = a0;
    iam[(b * 4 + 1) * HW + hw] = a1;
    iam[(b * 4 + 2) * HW + hw] = a2;
    iam[(b * 4 + 3) * HW + hw] = a3;
}

__device__ __forceinline__ float sigmoidf_dev(float x) {
    return 1.f / (1.f + expf(-x));
}

__global__ __launch_bounds__(256) void stats_kernel(
    const float* __restrict__ iam, int* __restrict__ pos, float* __restrict__ denom)
{
    const int i = blockIdx.x;
    const int tid = threadIdx.x;
    const float* p = &iam[i * HW];
    float bm = -1e30f; int bi = 0; float sum = 0.f;
    for (int l = tid; l < HW; l += 256) {
        const float s = sigmoidf_dev(p[l]);
        sum += s;
        if (s > bm) { bm = s; bi = l; }
    }
    __shared__ float sm[256]; __shared__ int si[256]; __shared__ float ss[256];
    sm[tid] = bm; si[tid] = bi; ss[tid] = sum;
    __syncthreads();
    for (int off = 128; off > 0; off >>= 1) {
        if (tid < off) {
            ss[tid] += ss[tid + off];
            const float m2 = sm[tid + off]; const int i2 = si[tid + off];
            if (m2 > sm[tid] || (m2 == sm[tid] && i2 < si[tid])) { sm[tid] = m2; si[tid] = i2; }
        }
        __syncthreads();
    }
    if (tid == 0) { pos[i] = si[0]; denom[i] = fmaxf(ss[0], 1e-6f); }
}

// inst[b][n][c] via planar hi+lo; grid (16 images, 17 planes)
__global__ __launch_bounds__(256) void inst_nhwc(
    const u16* __restrict__ fhi, const u16* __restrict__ flo,
    const float* __restrict__ iam, const float* __restrict__ denom,
    float* __restrict__ inst)
{
    const int b = blockIdx.x, g = blockIdx.y;
    const int tid = threadIdx.x;
    float acc[4][8] = {};
    const size_t pbase = (size_t)(b * 20 + g) * HPAD;
    for (int l = tid; l < HW; l += 256) {
        const int p = (l / 100 + 1) * 102 + (l % 100) + 1;
        s16x8 hv = *(const s16x8*)(fhi + (pbase + p) * 8);
        s16x8 lv = *(const s16x8*)(flo + (pbase + p) * 8);
        float fv[8];
        #pragma unroll
        for (int j = 0; j < 8; ++j) fv[j] = bf2f((u16)hv[j]) + bf2f((u16)lv[j]);
        #pragma unroll
        for (int n = 0; n < 4; ++n) {
            const float s = sigmoidf_dev(iam[(b * 4 + n) * HW + l]);
            #pragma unroll
            for (int j = 0; j < 8; ++j) acc[n][j] = fmaf(s, fv[j], acc[n][j]);
        }
    }
    __shared__ float red[128];
    const int lane = tid & 63, wid = tid >> 6;
    #pragma unroll
    for (int n = 0; n < 4; ++n)
        #pragma unroll
        for (int j = 0; j < 8; ++j) {
            float v = acc[n][j];
            #pragma unroll
            for (int off = 32; off > 0; off >>= 1) v += __shfl_xor(v, off);
            if (lane == 0) red[wid * 32 + n * 8 + j] = v;
        }
    __syncthreads();
    if (tid < 32) {
        const float s = red[tid] + red[32 + tid] + red[64 + tid] + red[96 + tid];
        const int n = tid >> 3, j = tid & 7;
        const int c = g * 8 + j;
        if (c < 134) inst[(b * 4 + n) * 134 + c] = s / denom[b * 4 + n];
    }
}

__global__ __launch_bounds__(128) void head_kernel(
    const float* __restrict__ inst,
    const float* __restrict__ cls_w, const float* __restrict__ cls_b,
    const float* __restrict__ mk_w, const float* __restrict__ mk_b,
    float* __restrict__ out_logits, float* __restrict__ pk)
{
    const int i = blockIdx.x;
    const int tid = threadIdx.x;
    __shared__ float iv[134];
    for (int c = tid; c < 134; c += 128) iv[c] = inst[i * 134 + c];
    __syncthreads();
    float a = mk_b[tid];
    for (int c = 0; c < 134; ++c) a = fmaf(iv[c], mk_w[tid * 134 + c], a);
    pk[i * 128 + tid] = a;
    if (tid < 2) {
        float g = cls_b[tid];
        for (int c = 0; c < 134; ++c) g = fmaf(iv[c], cls_w[tid * 134 + c], g);
        out_logits[i * 2 + tid] = g;
    }
}

__global__ void gather_nhwc(
    const u16* __restrict__ fhi, const u16* __restrict__ flo,
    const int* __restrict__ pos, float* __restrict__ outm, float* __restrict__ outr)
{
    const int i = blockIdx.x;
    const int c = threadIdx.x;
    if (c >= 134) return;
    const int p = pos[i];                          // batch-0 quirk preserved
    const int ph = (p / 100 + 1) * 102 + (p % 100) + 1;
    const size_t o = ((size_t)(c >> 3) * HPAD + ph) * 8 + (c & 7);   // b=0
    const float v = bf2f(fhi[o]) + bf2f(flo[o]);
    if (c < 67) outm[i * 67 + c] = v;
    else        outr[i * 67 + (c - 67)] = v;
}

// pred_masks from compact mf [m][128] f32
__global__ __launch_bounds__(256) void maskout_nhwc(
    const float* __restrict__ pk, const float* __restrict__ mf,
    float* __restrict__ outm)
{
    const int b = blockIdx.x, lc = blockIdx.y;
    const int tid = threadIdx.x;
    __shared__ float pks[4][128];
    for (int i = tid; i < 512; i += 256) pks[i >> 7][i & 127] = pk[b * 512 + i];
    __syncthreads();
    const int l = lc * 256 + tid;
    if (l >= HW) return;
    const float* row = mf + (size_t)(b * HW + l) * 128;
    float a[4] = {};
    for (int k = 0; k < 128; k += 4) {
        const f32x4 mv = *(const f32x4*)(row + k);
        #pragma unroll
        for (int n = 0; n < 4; ++n) {
            a[n] = fmaf(pks[n][k + 0], mv[0], a[n]);
            a[n] = fmaf(pks[n][k + 1], mv[1], a[n]);
            a[n] = fmaf(pks[n][k + 2], mv[2], a[n]);
            a[n] = fmaf(pks[n][k + 3], mv[3], a[n]);
        }
    }
    #pragma unroll
    for (int n = 0; n < 4; ++n) outm[(b * 4 + n) * HW + l] = a[n];
}

// ---------------------------------------------------------------------------
extern "C" void kernel_launch(void* const* d_in, const int* in_sizes, int n_in,
                              void* d_out, int out_size, void* d_ws, size_t ws_size,
                              hipStream_t stream)
{
    const float* features = (const float*)d_in[0];
    const float* iw0 = (const float*)d_in[1];
    const float* ib0 = (const float*)d_in[2];
    const float* iw1 = (const float*)d_in[3];
    const float* ib1 = (const float*)d_in[4];
    const float* iw2 = (const float*)d_in[5];
    const float* ib2 = (const float*)d_in[6];
    const float* iw3 = (const float*)d_in[7];
    const float* ib3 = (const float*)d_in[8];
    const float* iam_w = (const float*)d_in[9];
    const float* iam_b = (const float*)d_in[10];
    const float* cls_w = (const float*)d_in[11];
    const float* cls_b = (const float*)d_in[12];
    const float* mk_w = (const float*)d_in[13];
    const float* mk_b = (const float*)d_in[14];
    const float* mw0 = (const float*)d_in[15];
    const float* mb0 = (const float*)d_in[16];
    const float* mw1 = (const float*)d_in[17];
    const float* mb1 = (const float*)d_in[18];
    const float* mw2 = (const float*)d_in[19];
    const float* mb2 = (const float*)d_in[20];
    const float* mw3 = (const float*)d_in[21];
    const float* mb3 = (const float*)d_in[22];
    const float* pw = (const float*)d_in[23];
    const float* pb = (const float*)d_in[24];

    // weight image sizes (bytes): NRS*nCh*Npad*4*16
    constexpr size_t WI0 = (size_t)9 * 9 * 192 * 4 * 16;      // 995,328
    constexpr size_t WI123 = (size_t)9 * 5 * 192 * 4 * 16;    // 552,960
    constexpr size_t WM0 = (size_t)9 * 9 * 256 * 4 * 16;      // 1,327,104
    constexpr size_t WM123 = (size_t)9 * 8 * 256 * 4 * 16;    // 1,179,648
    constexpr size_t WPJ = (size_t)1 * 8 * 128 * 4 * 16;      // 65,536
    constexpr size_t PLANE = (size_t)HPAD * 16;               // 71,680 B
    constexpr size_t X0SZ = (size_t)16 * 36 * PLANE;          // 41,287,680
    constexpr size_t P20 = (size_t)16 * 20 * PLANE;           // 22,937,600
    constexpr size_t P32 = (size_t)16 * 32 * PLANE;           // 36,700,160
    constexpr size_t MFSZ = (size_t)16 * HW * 128 * 4;        // 32,768,000

    char* ws = (char*)d_ws;
    size_t off = 0;
    auto carve = [&](size_t bytes) { char* p = ws + off; off += (bytes + 255) & ~(size_t)255; return p; };
    u16* wi0h = (u16*)carve(WI0); u16* wi0l = (u16*)carve(WI0);
    u16* wi1h = (u16*)carve(WI123); u16* wi1l = (u16*)carve(WI123);
    u16* wi2h = (u16*)carve(WI123); u16* wi2l = (u16*)carve(WI123);
    u16* wi3h = (u16*)carve(WI123); u16* wi3l = (u16*)carve(WI123);
    u16* wm0h = (u16*)carve(WM0);
    u16* wm1h = (u16*)carve(WM123); u16* wm2h = (u16*)carve(WM123); u16* wm3h = (u16*)carve(WM123);
    u16* wpjh = (u16*)carve(WPJ);
    u16* X0hi = (u16*)carve(X0SZ);
    char* RGA = carve(X0SZ);        // X0lo -> MBhi(36.7MB)
    char* RGB = carve(2 * P20);     // RAhi+RAlo -> MAhi
    char* RGC = carve(2 * P20);     // RBhi+RBlo -> mf
    float* iamb = (float*)carve(1024000);
    int* pos = (int*)carve(256);
    float* denom = (float*)carve(256);
    float* instb = (float*)carve(34560);
    float* pkbuf = (float*)carve(32768);

    u16* X0lo = (u16*)RGA;
    u16* MBhi = (u16*)RGA;
    u16* RAhi = (u16*)RGB; u16* RAlo = (u16*)(RGB + P20);
    u16* MAhi = (u16*)RGB;
    u16* RBhi = (u16*)RGC; u16* RBlo = (u16*)(RGC + P20);
    float* mf = (float*)RGC;

    float* out_logits = (float*)d_out;          // 64*2
    float* out_mask = out_logits + 128;         // 64*67
    float* out_reg = out_mask + 64 * 67;        // 64*67
    float* out_masks = out_reg + 64 * 67;       // 64*4000

    const dim3 blk(256);
    auto rp = [&](const float* W, u16* h, u16* l, int Cout_, int Cin_, int NRS_,
                  int nCh_, int Npad_, int dolo) {
        const int tot = NRS_ * nCh_ * Npad_ * 4;
        repack_w<<<dim3((tot + 255) / 256), blk, 0, stream>>>(W, h, l, Cout_, Cin_, NRS_, nCh_, Npad_, dolo);
    };
    rp(iw0, wi0h, wi0l, 134, 258, 9, 9, 192, 1);
    rp(iw1, wi1h, wi1l, 134, 134, 9, 5, 192, 1);
    rp(iw2, wi2h, wi2l, 134, 134, 9, 5, 192, 1);
    rp(iw3, wi3h, wi3l, 134, 134, 9, 5, 192, 1);
    rp(mw0, wm0h, nullptr, 256, 258, 9, 9, 256, 0);
    rp(mw1, wm1h, nullptr, 256, 256, 9, 8, 256, 0);
    rp(mw2, wm2h, nullptr, 256, 256, 9, 8, 256, 0);
    rp(mw3, wm3h, nullptr, 256, 256, 9, 8, 256, 0);
    rp(pw, wpjh, nullptr, 128, 256, 1, 8, 128, 0);

    const dim3 gH((NPIXH + 255) / 256);
    prep_x0<<<gH, blk, 0, stream>>>(features, X0hi, X0lo);
    zero_halo_pl<<<gH, blk, 0, stream>>>(RAhi, RAlo, 20, 20);

    // ---- inst branch: SPLIT=3, BN=64 ----
    conv_mfma<3, 64, 9, 0><<<dim3(3, 32, 16), blk, 0, stream>>>(
        X0hi, X0lo, wi0h, wi0l, ib0, RAhi, RAlo, nullptr, 9, 192, 134, 160, 20, 1);
    zero_halo_pl<<<gH, blk, 0, stream>>>(RBhi, RBlo, 20, 20);
    conv_mfma<3, 64, 9, 0><<<dim3(3, 32, 16), blk, 0, stream>>>(
        RAhi, RAlo, wi1h, wi1l, ib1, RBhi, RBlo, nullptr, 5, 192, 134, 160, 20, 1);
    conv_mfma<3, 64, 9, 0><<<dim3(3, 32, 16), blk, 0, stream>>>(
        RBhi, RBlo, wi2h, wi2l, ib2, RAhi, RAlo, nullptr, 5, 192, 134, 160, 20, 1);
    conv_mfma<3, 64, 9, 0><<<dim3(3, 32, 16), blk, 0, stream>>>(
        RAhi, RAlo, wi3h, wi3l, ib3, RBhi, RBlo, nullptr, 5, 192, 134, 160, 20, 1);

    iam_conv_nhwc<<<dim3(250), blk, 0, stream>>>(RBhi, RBlo, iam_w, iam_b, iamb);
    stats_kernel<<<dim3(64), blk, 0, stream>>>(iamb, pos, denom);
    inst_nhwc<<<dim3(16, 17), blk, 0, stream>>>(RBhi, RBlo, iamb, denom, instb);
    head_kernel<<<dim3(64), dim3(128), 0, stream>>>(instb, cls_w, cls_b, mk_w, mk_b, out_logits, pkbuf);
    gather_nhwc<<<dim3(64), dim3(192), 0, stream>>>(RBhi, RBlo, pos, out_mask, out_reg);

    // ---- mask branch: SPLIT=1, BN=128 (MA aliases RA+, MB aliases X0lo) ----
    zero_halo_pl<<<gH, blk, 0, stream>>>(MAhi, MBhi, 32, 32);
    conv_mfma<1, 128, 9, 1><<<dim3(2, 32, 16), blk, 0, stream>>>(
        X0hi, nullptr, wm0h, nullptr, mb0, MAhi, nullptr, nullptr, 9, 256, 256, 256, 32, 1);
    conv_mfma<1, 128, 9, 1><<<dim3(2, 32, 16), blk, 0, stream>>>(
        MAhi, nullptr, wm1h, nullptr, mb1, MBhi, nullptr, nullptr, 8, 256, 256, 256, 32, 1);
    conv_mfma<1, 128, 9, 1><<<dim3(2, 32, 16), blk, 0, stream>>>(
        MBhi, nullptr, wm2h, nullptr, mb2, MAhi, nullptr, nullptr, 8, 256, 256, 256, 32, 1);
    conv_mfma<1, 128, 9, 1><<<dim3(2, 32, 16), blk, 0, stream>>>(
        MAhi, nullptr, wm3h, nullptr, mb3, MBhi, nullptr, nullptr, 8, 256, 256, 256, 32, 1);
    conv_mfma<1, 128, 1, 2><<<dim3(1, 32, 16), blk, 0, stream>>>(
        MBhi, nullptr, wpjh, nullptr, pb, nullptr, nullptr, mf, 8, 128, 128, 128, 0, 0);

    maskout_nhwc<<<dim3(16, 16), blk, 0, stream>>>(pkbuf, mf, out_masks);
}

// Round 5
// 1157.802 us; speedup vs baseline: 9.3659x; 1.0953x over previous
//
#include <hip/hip_runtime.h>
#include <hip/hip_bf16.h>
#include <math.h>

constexpr int HW = 4000;
constexpr int HP = 4284;            // haloed pixels per image (42*102)
constexpr int HPAD = 4480;          // plane stride in pixels (incl. staging slack)
constexpr int NPIXH = 16 * HP;      // 68544

typedef short s16x8 __attribute__((ext_vector_type(8)));
typedef float f32x4 __attribute__((ext_vector_type(4)));
typedef unsigned short u16x4 __attribute__((ext_vector_type(4)));
typedef unsigned short u16;

__device__ __forceinline__ u16 f2bf(float f) {
    __hip_bfloat16 h = __float2bfloat16(f);
    u16 b; __builtin_memcpy(&b, &h, 2); return b;
}
__device__ __forceinline__ float bf2f(u16 b) {
    __hip_bfloat16 h; __builtin_memcpy(&h, &b, 2); return __bfloat162float(h);
}

__device__ __forceinline__ void gload_lds16(const void* g, void* l) {
    __builtin_amdgcn_global_load_lds(
        (const __attribute__((address_space(1))) void*)g,
        (__attribute__((address_space(3))) void*)l, 16, 0, 0);
}

// ---------------------------------------------------------------------------
// Weight repack: OIHW fp32 -> [rs][ch][Npad*4 chunks][8] bf16 hi (+ lo).
// chunk q: f=q>>6, g=(q>>4)&3, rA=q&15 -> n=f*16+rA, c=ch*32+g*8+j
// ---------------------------------------------------------------------------
__global__ __launch_bounds__(256) void repack_w(
    const float* __restrict__ W, u16* __restrict__ Wh, u16* __restrict__ Wl,
    int Cout, int Cin, int NRS, int nCh, int Npad, int do_lo)
{
    const int chunk = blockIdx.x * 256 + threadIdx.x;
    const int per = Npad * 4;
    const int total = NRS * nCh * per;
    if (chunk >= total) return;
    const int q = chunk % per;
    const int t2 = chunk / per;
    const int ch = t2 % nCh;
    const int rs = t2 / nCh;
    const int f = q >> 6, g = (q >> 4) & 3, rA = q & 15;
    const int n = f * 16 + rA;
    u16x4 hp[2], lp[2];
    #pragma unroll
    for (int j = 0; j < 8; ++j) {
        const int c = ch * 32 + g * 8 + j;
        const float v = (n < Cout && c < Cin) ? W[((size_t)n * Cin + c) * NRS + rs] : 0.f;
        const u16 hb = f2bf(v);
        hp[j >> 2][j & 3] = hb;
        lp[j >> 2][j & 3] = f2bf(v - bf2f(hb));
    }
    const size_t o = (size_t)chunk * 8;
    *(u16x4*)(Wh + o) = hp[0]; *(u16x4*)(Wh + o + 4) = hp[1];
    if (do_lo) { *(u16x4*)(Wl + o) = lp[0]; *(u16x4*)(Wl + o + 4) = lp[1]; }
}

// ---------------------------------------------------------------------------
// features NCHW fp32 -> planar-chunked haloed bf16 hi+lo (36 planes of 8 ch)
// channels: 0=x, 1=y, 2..257=f, 258..287=0
// ---------------------------------------------------------------------------
__global__ __launch_bounds__(256) void prep_x0(
    const float* __restrict__ feat, u16* __restrict__ Xh, u16* __restrict__ Xl)
{
    const int p = blockIdx.x * 256 + threadIdx.x;
    if (p >= NPIXH) return;
    const int b = p / HP; const int rem = p - b * HP;
    const int hh = rem / 102, wp = rem - hh * 102;
    const bool halo = (hh == 0) | (hh == 41) | (wp == 0) | (wp == 101);
    const int h = hh - 1, w = wp - 1;
    const int hw = h * 100 + w;
    const float xw = -1.f + 2.f * (float)w / 99.f;
    const float yh = -1.f + 2.f * (float)h / 39.f;
    for (int g = 0; g < 36; ++g) {
        u16x4 hp[2], lp[2];
        #pragma unroll
        for (int j = 0; j < 8; ++j) {
            const int c = g * 8 + j;
            float v = 0.f;
            if (!halo) {
                if (c == 0) v = xw;
                else if (c == 1) v = yh;
                else if (c < 258) v = feat[((size_t)(b * 256 + (c - 2))) * HW + hw];
            }
            const u16 hb = f2bf(v);
            hp[j >> 2][j & 3] = hb;
            lp[j >> 2][j & 3] = f2bf(v - bf2f(hb));
        }
        const size_t o = ((size_t)(b * 36 + g) * HPAD + rem) * 8;
        *(u16x4*)(Xh + o) = hp[0]; *(u16x4*)(Xh + o + 4) = hp[1];
        *(u16x4*)(Xl + o) = lp[0]; *(u16x4*)(Xl + o + 4) = lp[1];
    }
}

// zero the halo ring of two planar buffers
__global__ __launch_bounds__(256) void zero_halo_pl(
    u16* __restrict__ pa, u16* __restrict__ pb, int nGa, int nGb)
{
    const int p = blockIdx.x * 256 + threadIdx.x;
    if (p >= NPIXH) return;
    const int b = p / HP; const int rem = p - b * HP;
    const int hh = rem / 102, wp = rem - hh * 102;
    if (!((hh == 0) | (hh == 41) | (wp == 0) | (wp == 101))) return;
    const u16x4 z = {0, 0, 0, 0};
    for (int g = 0; g < nGa; ++g) {
        const size_t o = ((size_t)(b * nGa + g) * HPAD + rem) * 8;
        *(u16x4*)(pa + o) = z; *(u16x4*)(pa + o + 4) = z;
    }
    if (pb)
        for (int g = 0; g < nGb; ++g) {
            const size_t o = ((size_t)(b * nGb + g) * HPAD + rem) * 8;
            *(u16x4*)(pb + o) = z; *(u16x4*)(pb + o + 4) = z;
        }
}

// ---------------------------------------------------------------------------
// bf16-MFMA implicit-GEMM conv on planar-chunked haloed input.
// Per 32-ch chunk: stage 4 planes x 384 px ONCE via global_load_lds (plane
// stride 390 px in LDS -> no 4-way group alias), then all NRS taps read
// shifted windows from LDS. Weights are loaded straight to REGISTERS
// (fragment-ordered repack -> coalesced 64-lane x 16B loads), next tap
// prefetched during current tap's MFMAs. Two barriers per chunk total.
// mfma(A=W, B=X): acc rows = channels (4/lane), cols = pixels.
// 1-D grid with XCD-bijective swizzle: the nN n-blocks of an m-tile run on
// the same XCD so X re-reads hit that XCD's L2.
// SPLIT 1: hi only. SPLIT 3: hi+lo (3 passes, argmax-safe).
// OUTMODE 0: planar hi+lo; 1: planar hi; 2: compact [m][CoutStore] f32.
// ---------------------------------------------------------------------------
template <int SPLIT, int BN, int NRS, int OUTMODE, int NCH>
__global__ __launch_bounds__(256, 3) void conv_mfma(
    const u16* __restrict__ Xhi, const u16* __restrict__ Xlo,
    const u16* __restrict__ Whi, const u16* __restrict__ Wlo,
    const float* __restrict__ bias,
    u16* __restrict__ Yhi, u16* __restrict__ Ylo, float* __restrict__ Yf,
    int Npad, int Cout, int CoutStore, int nGout, int do_relu,
    int nN, int cpx)
{
    constexpr int FW = BN / 32;          // n-frags per wave
    constexpr int PSTRIDE = 390;         // LDS plane stride in px (bank-spread)
    constexpr int NGIN = NCH * 4;        // input planes per image

    __shared__ u16 lsXh[4 * PSTRIDE * 8];
    __shared__ u16 lsXl[SPLIT == 3 ? 4 * PSTRIDE * 8 : 8];

    const int tid = threadIdx.x, lane = tid & 63, wid = tid >> 6;

    // XCD-bijective swizzle (nwg % 8 == 0 for all launches)
    const int pb_ = blockIdx.x;
    const int s = (pb_ & 7) * cpx + (pb_ >> 3);
    const int nb = s % nN;
    const int mt = s / nN;
    const int mb = mt & 31, bimg = mt >> 5;
    const int off = mb * 128;
    const int n0 = nb * BN;
    const int h0 = off / 100, w0 = off - h0 * 100;
    const int pTL0 = h0 * 102 + w0;

    const int wn = (wid & 1) * (BN / 2);
    const int wm = (wid >> 1) * 64;
    const int gA = lane >> 4, rA = lane & 15;
    const int wq0 = ((n0 + wn) >> 4) * 64;

    // per-lane pixel displacement for the 4 m-frags
    int pd[4]; bool mval[4];
    #pragma unroll
    for (int fb = 0; fb < 4; ++fb) {
        int mm = off + wm + fb * 16 + rA;
        mval[fb] = mm < HW;
        if (!mval[fb]) mm = HW - 1;
        const int h = mm / 100, w = mm - h * 100;
        pd[fb] = (h * 102 + w) - pTL0;
    }

    auto stageX = [&](int ch) {
        const size_t src = ((size_t)(bimg * NGIN + ch * 4 + wid) * HPAD + pTL0) * 8;
        char* dst = (char*)lsXh + wid * (PSTRIDE * 16);
        char* dstl = (char*)lsXl + wid * (PSTRIDE * 16);
        #pragma unroll
        for (int i = 0; i < 6; ++i) {
            gload_lds16(Xhi + src + (size_t)(i * 64 + lane) * 8, dst + i * 1024);
            if constexpr (SPLIT == 3)
                gload_lds16(Xlo + src + (size_t)(i * 64 + lane) * 8, dstl + i * 1024);
        }
    };

    s16x8 wh[2][FW];
    s16x8 wl[2][SPLIT == 3 ? FW : 1];
    auto loadW = [&](int ch, int rs, int buf) {
        const size_t base = (((size_t)rs * NCH + ch) * (Npad * 4) + wq0 + lane) * 8;
        #pragma unroll
        for (int fa = 0; fa < FW; ++fa) {
            wh[buf][fa] = *(const s16x8*)(Whi + base + fa * 64 * 8);
            if constexpr (SPLIT == 3)
                wl[buf][fa] = *(const s16x8*)(Wlo + base + fa * 64 * 8);
        }
    };

    f32x4 acc[FW][4];
    #pragma unroll
    for (int i = 0; i < FW; ++i)
        #pragma unroll
        for (int j = 0; j < 4; ++j) acc[i][j] = (f32x4){0.f, 0.f, 0.f, 0.f};

    #pragma unroll 1
    for (int ch = 0; ch < NCH; ++ch) {
        if (ch) __syncthreads();          // protect LDS overwrite
        stageX(ch);
        loadW(ch, 0, 0);
        __syncthreads();                  // X tile ready (drains vmcnt)

        #pragma unroll
        for (int rs = 0; rs < NRS; ++rs) {
            if (rs + 1 < NRS) loadW(ch, rs + 1, (rs + 1) & 1);
            const int toff = (NRS == 9) ? ((rs / 3) * 102 + (rs % 3)) : 103;

            s16x8 bX[4], bXl[SPLIT == 3 ? 4 : 1];
            #pragma unroll
            for (int fb = 0; fb < 4; ++fb) {
                const int xi = (gA * PSTRIDE + pd[fb] + toff) * 8;
                bX[fb] = *(const s16x8*)&lsXh[xi];
                if constexpr (SPLIT == 3) bXl[fb] = *(const s16x8*)&lsXl[xi];
            }
            #pragma unroll
            for (int fa = 0; fa < FW; ++fa)
                #pragma unroll
                for (int fb = 0; fb < 4; ++fb) {
                    acc[fa][fb] = __builtin_amdgcn_mfma_f32_16x16x32_bf16(
                        wh[rs & 1][fa], bX[fb], acc[fa][fb], 0, 0, 0);
                    if constexpr (SPLIT == 3) {
                        acc[fa][fb] = __builtin_amdgcn_mfma_f32_16x16x32_bf16(
                            wh[rs & 1][fa], bXl[fb], acc[fa][fb], 0, 0, 0);
                        acc[fa][fb] = __builtin_amdgcn_mfma_f32_16x16x32_bf16(
                            wl[rs & 1][fa], bX[fb], acc[fa][fb], 0, 0, 0);
                    }
                }
        }
    }

    // ---- epilogue ----
    #pragma unroll
    for (int fb = 0; fb < 4; ++fb) {
        if (!mval[fb]) continue;
        const int mm = off + wm + fb * 16 + rA;
        #pragma unroll
        for (int fa = 0; fa < FW; ++fa) {
            const int nbc = n0 + wn + fa * 16 + gA * 4;
            if (nbc >= CoutStore) continue;
            f32x4 v = acc[fa][fb];
            #pragma unroll
            for (int i = 0; i < 4; ++i) {
                const int n = nbc + i;
                float x = (n < Cout) ? (v[i] + bias[n]) : 0.f;
                if (do_relu) x = fmaxf(x, 0.f);
                v[i] = x;
            }
            if constexpr (OUTMODE == 2) {
                *(f32x4*)(Yf + (size_t)(bimg * HW + mm) * CoutStore + nbc) = v;
            } else {
                const size_t o =
                    ((size_t)(bimg * nGout + (nbc >> 3)) * HPAD + pTL0 + pd[fb] + 103) * 8 + (nbc & 7);
                u16x4 hp;
                #pragma unroll
                for (int i = 0; i < 4; ++i) hp[i] = f2bf(v[i]);
                *(u16x4*)(Yhi + o) = hp;
                if constexpr (OUTMODE == 0) {
                    u16x4 lp;
                    #pragma unroll
                    for (int i = 0; i < 4; ++i) lp[i] = f2bf(v[i] - bf2f(hp[i]));
                    *(u16x4*)(Ylo + o) = lp;
                }
            }
        }
    }
}

// ---------------------------------------------------------------------------
// iam conv: 4 outputs, 3x3, consumes planar hi+lo (fp32-equivalent), 20 planes
// ---------------------------------------------------------------------------
__global__ __launch_bounds__(256) void iam_conv_nhwc(
    const u16* __restrict__ fhi, const u16* __restrict__ flo,
    const float* __restrict__ Wt, const float* __restrict__ bias,
    float* __restrict__ iam)
{
    __shared__ float wsm[9 * 134 * 4];
    const int tid = threadIdx.x;
    for (int i = tid; i < 4824; i += 256) {
        const int rs = i / 536; const int rem = i - rs * 536;
        const int c = rem >> 2; const int n = rem & 3;
        wsm[i] = Wt[(n * 134 + c) * 9 + rs];
    }
    __syncthreads();
    const int m = blockIdx.x * 256 + tid;
    const int b = m / HW; const int hw = m - b * HW;
    const int h = hw / 100, w = hw - h * 100;
    const int pTL = h * 102 + w;
    float a0 = bias[0], a1 = bias[1], a2 = bias[2], a3 = bias[3];
    for (int rs = 0; rs < 9; ++rs) {
        const int pA = pTL + (rs / 3) * 102 + (rs % 3);
        const float* wrow = &wsm[rs * 536];
        for (int g = 0; g < 17; ++g) {
            const size_t o = ((size_t)(b * 20 + g) * HPAD + pA) * 8;
            s16x8 hv = *(const s16x8*)(fhi + o);
            s16x8 lv = *(const s16x8*)(flo + o);
            #pragma unroll
            for (int j = 0; j < 8; ++j) {
                const int c = g * 8 + j;
                if (c < 134) {
                    const float v = bf2f((u16)hv[j]) + bf2f((u16)lv[j]);
                    const float* wc = wrow + c * 4;
                    a0 = fmaf(v, wc[0], a0); a1 = fmaf(v, wc[1], a1);
                    a2 = fmaf(v, wc[2], a2); a3 = fmaf(v, wc[3], a3);
                }
            }
        }
    }
    iam[(b * 4 + 0) * HW + hw] = a0;
    iam[(b * 4 + 1) * HW + hw] = a1;
    iam[(b * 4 + 2) * HW + hw] = a2;
    iam[(b * 4 + 3) * HW + hw] = a3;
}

__device__ __forceinline__ float sigmoidf_dev(float x) {
    return 1.f / (1.f + expf(-x));
}

__global__ __launch_bounds__(256) void stats_kernel(
    const float* __restrict__ iam, int* __restrict__ pos, float* __restrict__ denom)
{
    const int i = blockIdx.x;
    const int tid = threadIdx.x;
    const float* p = &iam[i * HW];
    float bm = -1e30f; int bi = 0; float sum = 0.f;
    for (int l = tid; l < HW; l += 256) {
        const float s = sigmoidf_dev(p[l]);
        sum += s;
        if (s > bm) { bm = s; bi = l; }
    }
    __shared__ float sm[256]; __shared__ int si[256]; __shared__ float ss[256];
    sm[tid] = bm; si[tid] = bi; ss[tid] = sum;
    __syncthreads();
    for (int off = 128; off > 0; off >>= 1) {
        if (tid < off) {
            ss[tid] += ss[tid + off];
            const float m2 = sm[tid + off]; const int i2 = si[tid + off];
            if (m2 > sm[tid] || (m2 == sm[tid] && i2 < si[tid])) { sm[tid] = m2; si[tid] = i2; }
        }
        __syncthreads();
    }
    if (tid == 0) { pos[i] = si[0]; denom[i] = fmaxf(ss[0], 1e-6f); }
}

// inst[b][n][c] via planar hi+lo; grid (16 images, 17 planes)
__global__ __launch_bounds__(256) void inst_nhwc(
    const u16* __restrict__ fhi, const u16* __restrict__ flo,
    const float* __restrict__ iam, const float* __restrict__ denom,
    float* __restrict__ inst)
{
    const int b = blockIdx.x, g = blockIdx.y;
    const int tid = threadIdx.x;
    float acc[4][8] = {};
    const size_t pbase = (size_t)(b * 20 + g) * HPAD;
    for (int l = tid; l < HW; l += 256) {
        const int p = (l / 100 + 1) * 102 + (l % 100) + 1;
        s16x8 hv = *(const s16x8*)(fhi + (pbase + p) * 8);
        s16x8 lv = *(const s16x8*)(flo + (pbase + p) * 8);
        float fv[8];
        #pragma unroll
        for (int j = 0; j < 8; ++j) fv[j] = bf2f((u16)hv[j]) + bf2f((u16)lv[j]);
        #pragma unroll
        for (int n = 0; n < 4; ++n) {
            const float s = sigmoidf_dev(iam[(b * 4 + n) * HW + l]);
            #pragma unroll
            for (int j = 0; j < 8; ++j) acc[n][j] = fmaf(s, fv[j], acc[n][j]);
        }
    }
    __shared__ float red[128];
    const int lane = tid & 63, wid = tid >> 6;
    #pragma unroll
    for (int n = 0; n < 4; ++n)
        #pragma unroll
        for (int j = 0; j < 8; ++j) {
            float v = acc[n][j];
            #pragma unroll
            for (int off = 32; off > 0; off >>= 1) v += __shfl_xor(v, off);
            if (lane == 0) red[wid * 32 + n * 8 + j] = v;
        }
    __syncthreads();
    if (tid < 32) {
        const float s = red[tid] + red[32 + tid] + red[64 + tid] + red[96 + tid];
        const int n = tid >> 3, j = tid & 7;
        const int c = g * 8 + j;
        if (c < 134) inst[(b * 4 + n) * 134 + c] = s / denom[b * 4 + n];
    }
}

__global__ __launch_bounds__(128) void head_kernel(
    const float* __restrict__ inst,
    const float* __restrict__ cls_w, const float* __restrict__ cls_b,
    const float* __restrict__ mk_w, const float* __restrict__ mk_b,
    float* __restrict__ out_logits, float* __restrict__ pk)
{
    const int i = blockIdx.x;
    const int tid = threadIdx.x;
    __shared__ float iv[134];
    for (int c = tid; c < 134; c += 128) iv[c] = inst[i * 134 + c];
    __syncthreads();
    float a = mk_b[tid];
    for (int c = 0; c < 134; ++c) a = fmaf(iv[c], mk_w[tid * 134 + c], a);
    pk[i * 128 + tid] = a;
    if (tid < 2) {
        float g = cls_b[tid];
        for (int c = 0; c < 134; ++c) g = fmaf(iv[c], cls_w[tid * 134 + c], g);
        out_logits[i * 2 + tid] = g;
    }
}

__global__ void gather_nhwc(
    const u16* __restrict__ fhi, const u16* __restrict__ flo,
    const int* __restrict__ pos, float* __restrict__ outm, float* __restrict__ outr)
{
    const int i = blockIdx.x;
    const int c = threadIdx.x;
    if (c >= 134) return;
    const int p = pos[i];                          // batch-0 quirk preserved
    const int ph = (p / 100 + 1) * 102 + (p % 100) + 1;
    const size_t o = ((size_t)(c >> 3) * HPAD + ph) * 8 + (c & 7);   // b=0
    const float v = bf2f(fhi[o]) + bf2f(flo[o]);
    if (c < 67) outm[i * 67 + c] = v;
    else        outr[i * 67 + (c - 67)] = v;
}

// pred_masks from compact mf [m][128] f32
__global__ __launch_bounds__(256) void maskout_nhwc(
    const float* __restrict__ pk, const float* __restrict__ mf,
    float* __restrict__ outm)
{
    const int b = blockIdx.x, lc = blockIdx.y;
    const int tid = threadIdx.x;
    __shared__ float pks[4][128];
    for (int i = tid; i < 512; i += 256) pks[i >> 7][i & 127] = pk[b * 512 + i];
    __syncthreads();
    const int l = lc * 256 + tid;
    if (l >= HW) return;
    const float* row = mf + (size_t)(b * HW + l) * 128;
    float a[4] = {};
    for (int k = 0; k < 128; k += 4) {
        const f32x4 mv = *(const f32x4*)(row + k);
        #pragma unroll
        for (int n = 0; n < 4; ++n) {
            a[n] = fmaf(pks[n][k + 0], mv[0], a[n]);
            a[n] = fmaf(pks[n][k + 1], mv[1], a[n]);
            a[n] = fmaf(pks[n][k + 2], mv[2], a[n]);
            a[n] = fmaf(pks[n][k + 3], mv[3], a[n]);
        }
    }
    #pragma unroll
    for (int n = 0; n < 4; ++n) outm[(b * 4 + n) * HW + l] = a[n];
}

// ---------------------------------------------------------------------------
extern "C" void kernel_launch(void* const* d_in, const int* in_sizes, int n_in,
                              void* d_out, int out_size, void* d_ws, size_t ws_size,
                              hipStream_t stream)
{
    const float* features = (const float*)d_in[0];
    const float* iw0 = (const float*)d_in[1];
    const float* ib0 = (const float*)d_in[2];
    const float* iw1 = (const float*)d_in[3];
    const float* ib1 = (const float*)d_in[4];
    const float* iw2 = (const float*)d_in[5];
    const float* ib2 = (const float*)d_in[6];
    const float* iw3 = (const float*)d_in[7];
    const float* ib3 = (const float*)d_in[8];
    const float* iam_w = (const float*)d_in[9];
    const float* iam_b = (const float*)d_in[10];
    const float* cls_w = (const float*)d_in[11];
    const float* cls_b = (const float*)d_in[12];
    const float* mk_w = (const float*)d_in[13];
    const float* mk_b = (const float*)d_in[14];
    const float* mw0 = (const float*)d_in[15];
    const float* mb0 = (const float*)d_in[16];
    const float* mw1 = (const float*)d_in[17];
    const float* mb1 = (const float*)d_in[18];
    const float* mw2 = (const float*)d_in[19];
    const float* mb2 = (const float*)d_in[20];
    const float* mw3 = (const float*)d_in[21];
    const float* mb3 = (const float*)d_in[22];
    const float* pw = (const float*)d_in[23];
    const float* pb = (const float*)d_in[24];

    // weight image sizes (bytes): NRS*nCh*Npad*4*16
    constexpr size_t WI0 = (size_t)9 * 9 * 192 * 4 * 16;      // 995,328
    constexpr size_t WI123 = (size_t)9 * 5 * 192 * 4 * 16;    // 552,960
    constexpr size_t WM0 = (size_t)9 * 9 * 256 * 4 * 16;      // 1,327,104
    constexpr size_t WM123 = (size_t)9 * 8 * 256 * 4 * 16;    // 1,179,648
    constexpr size_t WPJ = (size_t)1 * 8 * 128 * 4 * 16;      // 65,536
    constexpr size_t PLANE = (size_t)HPAD * 16;               // 71,680 B
    constexpr size_t X0SZ = (size_t)16 * 36 * PLANE;          // 41,287,680
    constexpr size_t P20 = (size_t)16 * 20 * PLANE;           // 22,937,600

    char* ws = (char*)d_ws;
    size_t off = 0;
    auto carve = [&](size_t bytes) { char* p = ws + off; off += (bytes + 255) & ~(size_t)255; return p; };
    u16* wi0h = (u16*)carve(WI0); u16* wi0l = (u16*)carve(WI0);
    u16* wi1h = (u16*)carve(WI123); u16* wi1l = (u16*)carve(WI123);
    u16* wi2h = (u16*)carve(WI123); u16* wi2l = (u16*)carve(WI123);
    u16* wi3h = (u16*)carve(WI123); u16* wi3l = (u16*)carve(WI123);
    u16* wm0h = (u16*)carve(WM0);
    u16* wm1h = (u16*)carve(WM123); u16* wm2h = (u16*)carve(WM123); u16* wm3h = (u16*)carve(WM123);
    u16* wpjh = (u16*)carve(WPJ);
    u16* X0hi = (u16*)carve(X0SZ);
    char* RGA = carve(X0SZ);        // X0lo -> MBhi(36.7MB)
    char* RGB = carve(2 * P20);     // RAhi+RAlo -> MAhi
    char* RGC = carve(2 * P20);     // RBhi+RBlo -> mf
    float* iamb = (float*)carve(1024000);
    int* pos = (int*)carve(256);
    float* denom = (float*)carve(256);
    float* instb = (float*)carve(34560);
    float* pkbuf = (float*)carve(32768);

    u16* X0lo = (u16*)RGA;
    u16* MBhi = (u16*)RGA;
    u16* RAhi = (u16*)RGB; u16* RAlo = (u16*)(RGB + P20);
    u16* MAhi = (u16*)RGB;
    u16* RBhi = (u16*)RGC; u16* RBlo = (u16*)(RGC + P20);
    float* mf = (float*)RGC;

    float* out_logits = (float*)d_out;          // 64*2
    float* out_mask = out_logits + 128;         // 64*67
    float* out_reg = out_mask + 64 * 67;        // 64*67
    float* out_masks = out_reg + 64 * 67;       // 64*4000

    const dim3 blk(256);
    auto rp = [&](const float* W, u16* h, u16* l, int Cout_, int Cin_, int NRS_,
                  int nCh_, int Npad_, int dolo) {
        const int tot = NRS_ * nCh_ * Npad_ * 4;
        repack_w<<<dim3((tot + 255) / 256), blk, 0, stream>>>(W, h, l, Cout_, Cin_, NRS_, nCh_, Npad_, dolo);
    };
    rp(iw0, wi0h, wi0l, 134, 258, 9, 9, 192, 1);
    rp(iw1, wi1h, wi1l, 134, 134, 9, 5, 192, 1);
    rp(iw2, wi2h, wi2l, 134, 134, 9, 5, 192, 1);
    rp(iw3, wi3h, wi3l, 134, 134, 9, 5, 192, 1);
    rp(mw0, wm0h, nullptr, 256, 258, 9, 9, 256, 0);
    rp(mw1, wm1h, nullptr, 256, 256, 9, 8, 256, 0);
    rp(mw2, wm2h, nullptr, 256, 256, 9, 8, 256, 0);
    rp(mw3, wm3h, nullptr, 256, 256, 9, 8, 256, 0);
    rp(pw, wpjh, nullptr, 128, 256, 1, 8, 128, 0);

    const dim3 gH((NPIXH + 255) / 256);
    prep_x0<<<gH, blk, 0, stream>>>(features, X0hi, X0lo);
    zero_halo_pl<<<gH, blk, 0, stream>>>(RAhi, RAlo, 20, 20);

    // grids: 1-D, nwg = nN*32*16 (divisible by 8)
    // ---- inst branch: SPLIT=3, BN=64, nN=3 -> nwg=1536, cpx=192 ----
    conv_mfma<3, 64, 9, 0, 9><<<dim3(1536), blk, 0, stream>>>(
        X0hi, X0lo, wi0h, wi0l, ib0, RAhi, RAlo, nullptr, 192, 134, 160, 20, 1, 3, 192);
    zero_halo_pl<<<gH, blk, 0, stream>>>(RBhi, RBlo, 20, 20);
    conv_mfma<3, 64, 9, 0, 5><<<dim3(1536), blk, 0, stream>>>(
        RAhi, RAlo, wi1h, wi1l, ib1, RBhi, RBlo, nullptr, 192, 134, 160, 20, 1, 3, 192);
    conv_mfma<3, 64, 9, 0, 5><<<dim3(1536), blk, 0, stream>>>(
        RBhi, RBlo, wi2h, wi2l, ib2, RAhi, RAlo, nullptr, 192, 134, 160, 20, 1, 3, 192);
    conv_mfma<3, 64, 9, 0, 5><<<dim3(1536), blk, 0, stream>>>(
        RAhi, RAlo, wi3h, wi3l, ib3, RBhi, RBlo, nullptr, 192, 134, 160, 20, 1, 3, 192);

    iam_conv_nhwc<<<dim3(250), blk, 0, stream>>>(RBhi, RBlo, iam_w, iam_b, iamb);
    stats_kernel<<<dim3(64), blk, 0, stream>>>(iamb, pos, denom);
    inst_nhwc<<<dim3(16, 17), blk, 0, stream>>>(RBhi, RBlo, iamb, denom, instb);
    head_kernel<<<dim3(64), dim3(128), 0, stream>>>(instb, cls_w, cls_b, mk_w, mk_b, out_logits, pkbuf);
    gather_nhwc<<<dim3(64), dim3(192), 0, stream>>>(RBhi, RBlo, pos, out_mask, out_reg);

    // ---- mask branch: SPLIT=1, BN=128, nN=2 -> nwg=1024, cpx=128 ----
    zero_halo_pl<<<gH, blk, 0, stream>>>(MAhi, MBhi, 32, 32);
    conv_mfma<1, 128, 9, 1, 9><<<dim3(1024), blk, 0, stream>>>(
        X0hi, nullptr, wm0h, nullptr, mb0, MAhi, nullptr, nullptr, 256, 256, 256, 32, 1, 2, 128);
    conv_mfma<1, 128, 9, 1, 8><<<dim3(1024), blk, 0, stream>>>(
        MAhi, nullptr, wm1h, nullptr, mb1, MBhi, nullptr, nullptr, 256, 256, 256, 32, 1, 2, 128);
    conv_mfma<1, 128, 9, 1, 8><<<dim3(1024), blk, 0, stream>>>(
        MBhi, nullptr, wm2h, nullptr, mb2, MAhi, nullptr, nullptr, 256, 256, 256, 32, 1, 2, 128);
    conv_mfma<1, 128, 9, 1, 8><<<dim3(1024), blk, 0, stream>>>(
        MAhi, nullptr, wm3h, nullptr, mb3, MBhi, nullptr, nullptr, 256, 256, 256, 32, 1, 2, 128);
    // proj 1x1: nN=1 -> nwg=512, cpx=64
    conv_mfma<1, 128, 1, 2, 8><<<dim3(512), blk, 0, stream>>>(
        MBhi, nullptr, wpjh, nullptr, pb, nullptr, nullptr, mf, 128, 128, 128, 0, 0, 1, 64);

    maskout_nhwc<<<dim3(16, 16), blk, 0, stream>>>(pkbuf, mf, out_masks);
}